// Round 4
// baseline (575.837 us; speedup 1.0000x reference)
//
#include <hip/hip_runtime.h>
#include <stdint.h>

// Problem constants
#define Bb 8
#define Ss 2048
#define Dd 512
#define Hh 8
#define Ee 64
#define Oo 512
#define Ff 512   // H*E

typedef _Float16 half_t;
typedef __attribute__((ext_vector_type(8))) _Float16 f16x8;  // 8 fp16 (4 VGPRs)
typedef __attribute__((ext_vector_type(4))) float f32x4;     // MFMA acc
typedef __attribute__((ext_vector_type(4))) float f4;
typedef __attribute__((ext_vector_type(4))) half_t h16x4;

__device__ __forceinline__ float exp2_fast(float x) {
    float r; asm("v_exp_f32 %0, %1" : "=v"(r) : "v"(x)); return r;  // HW 2^x
}

// ---------------- query f32 -> f16 ----------------
__global__ __launch_bounds__(256) void k_cvt_x(const float* __restrict__ x,
                                               half_t* __restrict__ xh) {
    size_t i = ((size_t)blockIdx.x * 256 + threadIdx.x) * 4;
    f4 v = *(const f4*)(x + i);
    h16x4 o;
    o[0] = (half_t)v[0]; o[1] = (half_t)v[1]; o[2] = (half_t)v[2]; o[3] = (half_t)v[3];
    *(h16x4*)(xh + i) = o;
}

// -------- weights: Wq/Wk/Wv [H,D,E] -> f16 [H,E,D]; Wo [F,O] -> f16 [O,F] --------
__global__ __launch_bounds__(256) void k_cvt_w(const float* __restrict__ Wq, const float* __restrict__ Wk,
                                               const float* __restrict__ Wv, const float* __restrict__ Wo,
                                               half_t* __restrict__ WqT, half_t* __restrict__ WkT,
                                               half_t* __restrict__ WvT, half_t* __restrict__ WoT) {
    int t = blockIdx.x * 256 + threadIdx.x;            // 0 .. H*D*E-1 (== F*O-1)
    int h = t / (Dd * Ee); int rem = t - h * (Dd * Ee);
    int d = rem / Ee;      int e = rem - d * Ee;
    int ti = (h * Ee + e) * Dd + d;
    WqT[ti] = (half_t)Wq[t];
    WkT[ti] = (half_t)Wk[t];
    WvT[ti] = (half_t)Wv[t];
    int f = t / Oo; int o = t - f * Oo;
    WoT[o * Ff + f] = (half_t)Wo[t];
}

// ---------------- fused QKV projection ----------------
// grid (S/64, B*H), 256 thr (4 waves x 16 rows). Per wave: 16x64 out, K=512.
// V is written TRANSPOSED: Vt[bh][e][s]  (so k_attn reads V^T B-frags from L2)
__global__ __launch_bounds__(256) void k_qkv(const half_t* __restrict__ xh,
                                             const half_t* __restrict__ WqT,
                                             const half_t* __restrict__ WkT,
                                             const half_t* __restrict__ WvT,
                                             half_t* __restrict__ Q,
                                             half_t* __restrict__ K,
                                             half_t* __restrict__ Vt) {
    int st = blockIdx.x, bh = blockIdx.y;
    int b = bh >> 3, h = bh & 7;
    int wave = threadIdx.x >> 6, lane = threadIdx.x & 63;
    int ar = lane & 15, kg = lane >> 4;

    const half_t* xr  = xh + ((size_t)b * Ss + st * 64 + wave * 16 + ar) * Dd + kg * 8;
    const half_t* wqb = WqT + (size_t)h * Ee * Dd + (size_t)ar * Dd + kg * 8;
    const half_t* wkb = WkT + (size_t)h * Ee * Dd + (size_t)ar * Dd + kg * 8;
    const half_t* wvb = WvT + (size_t)h * Ee * Dd + (size_t)ar * Dd + kg * 8;

    f32x4 aq[4], ak[4], av[4];
#pragma unroll
    for (int i = 0; i < 4; ++i) { aq[i] = (f32x4){0,0,0,0}; ak[i] = (f32x4){0,0,0,0}; av[i] = (f32x4){0,0,0,0}; }

    for (int k0 = 0; k0 < Dd; k0 += 32) {
        f16x8 a = *(const f16x8*)(xr + k0);
#pragma unroll
        for (int sub = 0; sub < 4; ++sub) {
            f16x8 bq = *(const f16x8*)(wqb + (size_t)sub * 16 * Dd + k0);
            aq[sub] = __builtin_amdgcn_mfma_f32_16x16x32_f16(a, bq, aq[sub], 0, 0, 0);
            f16x8 bk = *(const f16x8*)(wkb + (size_t)sub * 16 * Dd + k0);
            ak[sub] = __builtin_amdgcn_mfma_f32_16x16x32_f16(a, bk, ak[sub], 0, 0, 0);
            f16x8 bv = *(const f16x8*)(wvb + (size_t)sub * 16 * Dd + k0);
            av[sub] = __builtin_amdgcn_mfma_f32_16x16x32_f16(a, bv, av[sub], 0, 0, 0);
        }
    }
    // C/D layout: col = lane&15, row = (lane>>4)*4 + r   [measured m89]
    size_t obase = ((size_t)bh * Ss + st * 64 + wave * 16) * Ee;
#pragma unroll
    for (int sub = 0; sub < 4; ++sub)
#pragma unroll
        for (int r = 0; r < 4; ++r) {
            int s_loc = st * 64 + wave * 16 + kg * 4 + r;
            size_t oi = obase + (size_t)(kg * 4 + r) * Ee + sub * 16 + ar;
            Q[oi] = (half_t)aq[sub][r];
            K[oi] = (half_t)ak[sub][r];
            Vt[((size_t)bh * Ee + sub * 16 + ar) * Ss + s_loc] = (half_t)av[sub][r];
        }
}

// ---------------- flash-style causal attention (barrier-free, dual-head) ----------------
// 1024 one-D blocks; decode: xcd = b&7 owns heads [xcd*8, xcd*8+8) -> K/V L2-resident.
// Each block: ONE q-tile (64 rows) x TWO heads (independent streams A/B for ILP).
// qt descending in dispatch order (longest-first). 4 waves x 16 q-rows.
// K and V^T fragments straight from L2; P via per-wave LDS slice. No barriers.
__global__ __launch_bounds__(256, 3) void k_attn(const half_t* __restrict__ Q,
                                                 const half_t* __restrict__ Kg,
                                                 const half_t* __restrict__ Vtg,
                                                 half_t* __restrict__ ctx) {
    __shared__ __attribute__((aligned(16))) half_t Pl[4][2][16][72];  // [wave][stream][q][k]

    int bid = blockIdx.x;                 // 0..1023
    int xcd = bid & 7;
    int pl  = (bid >> 3) & 3;             // pair-local within XCD
    int qt  = 31 - (bid >> 5);            // 31..0 (longest first)
    int bhp = xcd * 4 + pl;               // head-pair 0..31
    int bh0 = bhp * 2, bh1 = bh0 + 1;

    int wave = threadIdx.x >> 6, lane = threadIdx.x & 63;
    int ar = lane & 15, kg = lane >> 4;
    int q0 = qt * 64;

    const half_t* QbA = Q   + (size_t)bh0 * Ss * Ee;
    const half_t* KbA = Kg  + (size_t)bh0 * Ss * Ee;
    const half_t* VbA = Vtg + (size_t)bh0 * Ee * Ss;
    const half_t* QbB = Q   + (size_t)bh1 * Ss * Ee;
    const half_t* KbB = Kg  + (size_t)bh1 * Ss * Ee;
    const half_t* VbB = Vtg + (size_t)bh1 * Ee * Ss;

    // Q A-frags, pre-scaled by log2(e) so softmax runs in exp2 domain
    const half_t l2e = (half_t)1.44269504f;
    const half_t* qpA = QbA + (size_t)(q0 + wave * 16 + ar) * Ee + kg * 8;
    const half_t* qpB = QbB + (size_t)(q0 + wave * 16 + ar) * Ee + kg * 8;
    f16x8 qfA0 = *(const f16x8*)qpA;
    f16x8 qfA1 = *(const f16x8*)(qpA + 32);
    f16x8 qfB0 = *(const f16x8*)qpB;
    f16x8 qfB1 = *(const f16x8*)(qpB + 32);
#pragma unroll
    for (int j = 0; j < 8; ++j) { qfA0[j] *= l2e; qfA1[j] *= l2e; qfB0[j] *= l2e; qfB1[j] *= l2e; }

    f32x4 oA[4], oB[4]; float mA[4], lA[4], mB[4], lB[4];
#pragma unroll
    for (int i = 0; i < 4; ++i) {
        oA[i] = (f32x4){0,0,0,0}; oB[i] = (f32x4){0,0,0,0};
        mA[i] = -1e30f; lA[i] = 0.f; mB[i] = -1e30f; lB[i] = 0.f;
    }

    for (int kt = 0; kt <= qt; ++kt) {
        int k0 = kt * 64;
        // ---- QK^T for both streams (independent chains) ----
        f32x4 sA[4], sB[4];
        __builtin_amdgcn_s_setprio(1);
#pragma unroll
        for (int sub = 0; sub < 4; ++sub) {
            sA[sub] = (f32x4){0,0,0,0};
            const half_t* kp = KbA + (size_t)(k0 + sub * 16 + ar) * Ee + kg * 8;
            f16x8 kf0 = *(const f16x8*)kp;
            sA[sub] = __builtin_amdgcn_mfma_f32_16x16x32_f16(qfA0, kf0, sA[sub], 0, 0, 0);
            f16x8 kf1 = *(const f16x8*)(kp + 32);
            sA[sub] = __builtin_amdgcn_mfma_f32_16x16x32_f16(qfA1, kf1, sA[sub], 0, 0, 0);
        }
#pragma unroll
        for (int sub = 0; sub < 4; ++sub) {
            sB[sub] = (f32x4){0,0,0,0};
            const half_t* kp = KbB + (size_t)(k0 + sub * 16 + ar) * Ee + kg * 8;
            f16x8 kf0 = *(const f16x8*)kp;
            sB[sub] = __builtin_amdgcn_mfma_f32_16x16x32_f16(qfB0, kf0, sB[sub], 0, 0, 0);
            f16x8 kf1 = *(const f16x8*)(kp + 32);
            sB[sub] = __builtin_amdgcn_mfma_f32_16x16x32_f16(qfB1, kf1, sB[sub], 0, 0, 0);
        }
        __builtin_amdgcn_s_setprio(0);
        if (kt == qt) {  // causal mask on the diagonal tile (same for both heads)
#pragma unroll
            for (int sub = 0; sub < 4; ++sub)
#pragma unroll
                for (int r = 0; r < 4; ++r)
                    if (sub * 16 + ar > wave * 16 + kg * 4 + r) { sA[sub][r] = -1e30f; sB[sub][r] = -1e30f; }
        }
        // ---- online softmax, stream A then B (compiler interleaves) ----
#pragma unroll
        for (int r = 0; r < 4; ++r) {
            float mt = fmaxf(fmaxf(sA[0][r], sA[1][r]), fmaxf(sA[2][r], sA[3][r]));
            mt = fmaxf(mt, __shfl_xor(mt, 1));
            mt = fmaxf(mt, __shfl_xor(mt, 2));
            mt = fmaxf(mt, __shfl_xor(mt, 4));
            mt = fmaxf(mt, __shfl_xor(mt, 8));
            float mn = fmaxf(mA[r], mt);
            float sc = exp2_fast(mA[r] - mn);
            float rs = 0.f;
#pragma unroll
            for (int sub = 0; sub < 4; ++sub) {
                float p = exp2_fast(sA[sub][r] - mn);
                rs += p;
                Pl[wave][0][kg * 4 + r][sub * 16 + ar] = (half_t)p;
            }
            rs += __shfl_xor(rs, 1);
            rs += __shfl_xor(rs, 2);
            rs += __shfl_xor(rs, 4);
            rs += __shfl_xor(rs, 8);
            lA[r] = lA[r] * sc + rs;
            mA[r] = mn;
            oA[0][r] *= sc; oA[1][r] *= sc; oA[2][r] *= sc; oA[3][r] *= sc;
        }
#pragma unroll
        for (int r = 0; r < 4; ++r) {
            float mt = fmaxf(fmaxf(sB[0][r], sB[1][r]), fmaxf(sB[2][r], sB[3][r]));
            mt = fmaxf(mt, __shfl_xor(mt, 1));
            mt = fmaxf(mt, __shfl_xor(mt, 2));
            mt = fmaxf(mt, __shfl_xor(mt, 4));
            mt = fmaxf(mt, __shfl_xor(mt, 8));
            float mn = fmaxf(mB[r], mt);
            float sc = exp2_fast(mB[r] - mn);
            float rs = 0.f;
#pragma unroll
            for (int sub = 0; sub < 4; ++sub) {
                float p = exp2_fast(sB[sub][r] - mn);
                rs += p;
                Pl[wave][1][kg * 4 + r][sub * 16 + ar] = (half_t)p;
            }
            rs += __shfl_xor(rs, 1);
            rs += __shfl_xor(rs, 2);
            rs += __shfl_xor(rs, 4);
            rs += __shfl_xor(rs, 8);
            lB[r] = lB[r] * sc + rs;
            mB[r] = mn;
            oB[0][r] *= sc; oB[1][r] *= sc; oB[2][r] *= sc; oB[3][r] *= sc;
        }
        // ---- PV for both streams ----
        f16x8 pfA0 = *(const f16x8*)&Pl[wave][0][ar][kg * 8];
        f16x8 pfA1 = *(const f16x8*)&Pl[wave][0][ar][32 + kg * 8];
        f16x8 pfB0 = *(const f16x8*)&Pl[wave][1][ar][kg * 8];
        f16x8 pfB1 = *(const f16x8*)&Pl[wave][1][ar][32 + kg * 8];
        __builtin_amdgcn_s_setprio(1);
#pragma unroll
        for (int sub = 0; sub < 4; ++sub) {
            const half_t* vp = VbA + (size_t)(sub * 16 + ar) * Ss + k0 + kg * 8;
            f16x8 vf0 = *(const f16x8*)vp;
            oA[sub] = __builtin_amdgcn_mfma_f32_16x16x32_f16(pfA0, vf0, oA[sub], 0, 0, 0);
            f16x8 vf1 = *(const f16x8*)(vp + 32);
            oA[sub] = __builtin_amdgcn_mfma_f32_16x16x32_f16(pfA1, vf1, oA[sub], 0, 0, 0);
        }
#pragma unroll
        for (int sub = 0; sub < 4; ++sub) {
            const half_t* vp = VbB + (size_t)(sub * 16 + ar) * Ss + k0 + kg * 8;
            f16x8 vf0 = *(const f16x8*)vp;
            oB[sub] = __builtin_amdgcn_mfma_f32_16x16x32_f16(pfB0, vf0, oB[sub], 0, 0, 0);
            f16x8 vf1 = *(const f16x8*)(vp + 32);
            oB[sub] = __builtin_amdgcn_mfma_f32_16x16x32_f16(pfB1, vf1, oB[sub], 0, 0, 0);
        }
        __builtin_amdgcn_s_setprio(0);
    }
    // epilogue: ctx[b, s, h*E + e] f16 (head-major concat), both streams
    int b0 = bh0 >> 3, h0 = bh0 & 7;
    int b1 = bh1 >> 3, h1 = bh1 & 7;
#pragma unroll
    for (int sub = 0; sub < 4; ++sub)
#pragma unroll
        for (int r = 0; r < 4; ++r) {
            int row = q0 + wave * 16 + kg * 4 + r;
            ctx[((size_t)b0 * Ss + row) * Ff + h0 * Ee + sub * 16 + ar] = (half_t)(oA[sub][r] / lA[r]);
            ctx[((size_t)b1 * Ss + row) * Ff + h1 * Ee + sub * 16 + ar] = (half_t)(oB[sub][r] / lB[r]);
        }
}

// ---------------- output projection: ctx[16384,512] x WoT -> out f32 ----------------
// grid (M/64, O/64) = (256, 8)
__global__ __launch_bounds__(256) void k_proj(const half_t* __restrict__ ctx,
                                              const half_t* __restrict__ WoT,
                                              float* __restrict__ out) {
    int mt = blockIdx.x, ot = blockIdx.y;
    int wave = threadIdx.x >> 6, lane = threadIdx.x & 63;
    int ar = lane & 15, kg = lane >> 4;

    const half_t* arow = ctx + ((size_t)mt * 64 + wave * 16 + ar) * Ff + kg * 8;
    const half_t* brow = WoT + ((size_t)ot * 64 + ar) * Ff + kg * 8;

    f32x4 acc[4];
#pragma unroll
    for (int i = 0; i < 4; ++i) acc[i] = (f32x4){0,0,0,0};

    for (int k0 = 0; k0 < Ff; k0 += 32) {
        f16x8 a = *(const f16x8*)(arow + k0);
#pragma unroll
        for (int sub = 0; sub < 4; ++sub) {
            f16x8 b = *(const f16x8*)(brow + (size_t)sub * 16 * Ff + k0);
            acc[sub] = __builtin_amdgcn_mfma_f32_16x16x32_f16(a, b, acc[sub], 0, 0, 0);
        }
    }
#pragma unroll
    for (int sub = 0; sub < 4; ++sub)
#pragma unroll
        for (int r = 0; r < 4; ++r)
            out[((size_t)mt * 64 + wave * 16 + kg * 4 + r) * Oo + ot * 64 + sub * 16 + ar] = acc[sub][r];
}

extern "C" void kernel_launch(void* const* d_in, const int* in_sizes, int n_in,
                              void* d_out, int out_size, void* d_ws, size_t ws_size,
                              hipStream_t stream) {
    const float* x  = (const float*)d_in[0];
    const float* Wq = (const float*)d_in[1];
    const float* Wk = (const float*)d_in[2];
    const float* Wv = (const float*)d_in[3];
    const float* Wo = (const float*)d_in[4];
    float* out = (float*)d_out;

    // workspace layout (all f16, fully rewritten every call): ~86 MB
    char* ws = (char*)d_ws;
    size_t off = 0;
    half_t* xh  = (half_t*)(ws + off); off += (size_t)Bb * Ss * Dd * 2;   // 16 MB
    half_t* WqT = (half_t*)(ws + off); off += (size_t)Hh * Ee * Dd * 2;
    half_t* WkT = (half_t*)(ws + off); off += (size_t)Hh * Ee * Dd * 2;
    half_t* WvT = (half_t*)(ws + off); off += (size_t)Hh * Ee * Dd * 2;
    half_t* WoT = (half_t*)(ws + off); off += (size_t)Ff * Oo * 2;
    half_t* Qd  = (half_t*)(ws + off); off += (size_t)Bb * Hh * Ss * Ee * 2;
    half_t* Kd  = (half_t*)(ws + off); off += (size_t)Bb * Hh * Ss * Ee * 2;
    half_t* Vtd = (half_t*)(ws + off); off += (size_t)Bb * Hh * Ss * Ee * 2;  // transposed [bh][e][s]
    half_t* ctx = (half_t*)(ws + off); off += (size_t)Bb * Ss * Ff * 2;

    k_cvt_x<<<8192, 256, 0, stream>>>(x, xh);
    k_cvt_w<<<1024, 256, 0, stream>>>(Wq, Wk, Wv, Wo, WqT, WkT, WvT, WoT);
    k_qkv<<<dim3(Ss / 64, Bb * Hh), 256, 0, stream>>>(xh, WqT, WkT, WvT, Qd, Kd, Vtd);
    k_attn<<<1024, 256, 0, stream>>>(Qd, Kd, Vtd, ctx);
    k_proj<<<dim3((Bb * Ss) / 64, Oo / 64), 256, 0, stream>>>(ctx, WoT, out);
}

// Round 5
// 563.408 us; speedup vs baseline: 1.0221x; 1.0221x over previous
//
#include <hip/hip_runtime.h>
#include <stdint.h>

// Problem constants
#define Bb 8
#define Ss 2048
#define Dd 512
#define Hh 8
#define Ee 64
#define Oo 512
#define Ff 512   // H*E

typedef _Float16 half_t;
typedef __attribute__((ext_vector_type(8))) _Float16 f16x8;  // 8 fp16 (4 VGPRs)
typedef __attribute__((ext_vector_type(4))) float f32x4;     // MFMA acc
typedef __attribute__((ext_vector_type(4))) float f4;
typedef __attribute__((ext_vector_type(4))) half_t h16x4;

__device__ __forceinline__ float exp2_fast(float x) {
    float r; asm("v_exp_f32 %0, %1" : "=v"(r) : "v"(x)); return r;  // HW 2^x
}

// ---------------- query f32 -> f16 ----------------
__global__ __launch_bounds__(256) void k_cvt_x(const float* __restrict__ x,
                                               half_t* __restrict__ xh) {
    size_t i = ((size_t)blockIdx.x * 256 + threadIdx.x) * 4;
    f4 v = *(const f4*)(x + i);
    h16x4 o;
    o[0] = (half_t)v[0]; o[1] = (half_t)v[1]; o[2] = (half_t)v[2]; o[3] = (half_t)v[3];
    *(h16x4*)(xh + i) = o;
}

// -------- weights: Wq/Wk/Wv [H,D,E] -> f16 [H,E,D]; Wo [F,O] -> f16 [O,F] --------
__global__ __launch_bounds__(256) void k_cvt_w(const float* __restrict__ Wq, const float* __restrict__ Wk,
                                               const float* __restrict__ Wv, const float* __restrict__ Wo,
                                               half_t* __restrict__ WqT, half_t* __restrict__ WkT,
                                               half_t* __restrict__ WvT, half_t* __restrict__ WoT) {
    int t = blockIdx.x * 256 + threadIdx.x;            // 0 .. H*D*E-1 (== F*O-1)
    int h = t / (Dd * Ee); int rem = t - h * (Dd * Ee);
    int d = rem / Ee;      int e = rem - d * Ee;
    int ti = (h * Ee + e) * Dd + d;
    WqT[ti] = (half_t)Wq[t];
    WkT[ti] = (half_t)Wk[t];
    WvT[ti] = (half_t)Wv[t];
    int f = t / Oo; int o = t - f * Oo;
    WoT[o * Ff + f] = (half_t)Wo[t];
}

// ---------------- fused QKV projection ----------------
// grid (S/64, B*H), 256 thr (4 waves x 16 rows). Per wave: 16x64 out, K=512.
// V is written TRANSPOSED: Vt[bh][e][s]  (so k_attn reads V^T B-frags from L2)
__global__ __launch_bounds__(256) void k_qkv(const half_t* __restrict__ xh,
                                             const half_t* __restrict__ WqT,
                                             const half_t* __restrict__ WkT,
                                             const half_t* __restrict__ WvT,
                                             half_t* __restrict__ Q,
                                             half_t* __restrict__ K,
                                             half_t* __restrict__ Vt) {
    int st = blockIdx.x, bh = blockIdx.y;
    int b = bh >> 3, h = bh & 7;
    int wave = threadIdx.x >> 6, lane = threadIdx.x & 63;
    int ar = lane & 15, kg = lane >> 4;

    const half_t* xr  = xh + ((size_t)b * Ss + st * 64 + wave * 16 + ar) * Dd + kg * 8;
    const half_t* wqb = WqT + (size_t)h * Ee * Dd + (size_t)ar * Dd + kg * 8;
    const half_t* wkb = WkT + (size_t)h * Ee * Dd + (size_t)ar * Dd + kg * 8;
    const half_t* wvb = WvT + (size_t)h * Ee * Dd + (size_t)ar * Dd + kg * 8;

    f32x4 aq[4], ak[4], av[4];
#pragma unroll
    for (int i = 0; i < 4; ++i) { aq[i] = (f32x4){0,0,0,0}; ak[i] = (f32x4){0,0,0,0}; av[i] = (f32x4){0,0,0,0}; }

    for (int k0 = 0; k0 < Dd; k0 += 32) {
        f16x8 a = *(const f16x8*)(xr + k0);
#pragma unroll
        for (int sub = 0; sub < 4; ++sub) {
            f16x8 bq = *(const f16x8*)(wqb + (size_t)sub * 16 * Dd + k0);
            aq[sub] = __builtin_amdgcn_mfma_f32_16x16x32_f16(a, bq, aq[sub], 0, 0, 0);
            f16x8 bk = *(const f16x8*)(wkb + (size_t)sub * 16 * Dd + k0);
            ak[sub] = __builtin_amdgcn_mfma_f32_16x16x32_f16(a, bk, ak[sub], 0, 0, 0);
            f16x8 bv = *(const f16x8*)(wvb + (size_t)sub * 16 * Dd + k0);
            av[sub] = __builtin_amdgcn_mfma_f32_16x16x32_f16(a, bv, av[sub], 0, 0, 0);
        }
    }
    // C/D layout: col = lane&15, row = (lane>>4)*4 + r   [measured m89]
    size_t obase = ((size_t)bh * Ss + st * 64 + wave * 16) * Ee;
#pragma unroll
    for (int sub = 0; sub < 4; ++sub)
#pragma unroll
        for (int r = 0; r < 4; ++r) {
            int s_loc = st * 64 + wave * 16 + kg * 4 + r;
            size_t oi = obase + (size_t)(kg * 4 + r) * Ee + sub * 16 + ar;
            Q[oi] = (half_t)aq[sub][r];
            K[oi] = (half_t)ak[sub][r];
            Vt[((size_t)bh * Ee + sub * 16 + ar) * Ss + s_loc] = (half_t)av[sub][r];
        }
}

// ---------------- flash-style causal attention (barrier-free, TLP-max) ----------------
// 2048 one-D blocks = 8 blocks/CU = 32 waves/CU (needs VGPR<=64 -> launch_bounds(256,8)).
// Decode: xcd = bid&7 owns heads [xcd*8, xcd*8+8) -> that XCD's K+V = 4MB = its L2.
// qt descending in dispatch order (longest-first); imbalance hidden by 8-deep waves.
// Each block: ONE q-tile (64 rows) x ONE head; 4 waves x 16 q-rows; no barriers.
__global__ __launch_bounds__(256, 8) void k_attn(const half_t* __restrict__ Q,
                                                 const half_t* __restrict__ Kg,
                                                 const half_t* __restrict__ Vtg,
                                                 half_t* __restrict__ ctx) {
    __shared__ __attribute__((aligned(16))) half_t Pl[4][16][72];   // per-wave P tile [q][k]

    int bid = blockIdx.x;                 // 0..2047
    int xcd = bid & 7;
    int idx = bid >> 3;                   // 0..255
    int qt  = 31 - (idx >> 3);            // 31..0 (longest first)
    int bh  = xcd * 8 + (idx & 7);        // head 0..63, 8 heads per XCD

    int wave = threadIdx.x >> 6, lane = threadIdx.x & 63;
    int ar = lane & 15, kg = lane >> 4;
    int q0 = qt * 64;

    const half_t* Qb = Q   + (size_t)bh * Ss * Ee;
    const half_t* Kb = Kg  + (size_t)bh * Ss * Ee;
    const half_t* Vb = Vtg + (size_t)bh * Ee * Ss;

    // Q A-frags, pre-scaled by log2(e) so softmax runs in exp2 domain
    const half_t* qp = Qb + (size_t)(q0 + wave * 16 + ar) * Ee + kg * 8;
    f16x8 qf0 = *(const f16x8*)qp;
    f16x8 qf1 = *(const f16x8*)(qp + 32);
    const half_t l2e = (half_t)1.44269504f;
#pragma unroll
    for (int j = 0; j < 8; ++j) { qf0[j] *= l2e; qf1[j] *= l2e; }

    f32x4 o[4]; float m[4], l[4];
#pragma unroll
    for (int i = 0; i < 4; ++i) { o[i] = (f32x4){0,0,0,0}; m[i] = -1e30f; l[i] = 0.f; }

    // per-lane bases (advance per kt; K sub-offsets fold into imm)
    const half_t* kp  = Kb + (size_t)ar * Ee + kg * 8;        // +64*Ee per kt
    const half_t* vpb = Vb + (size_t)ar * Ss + kg * 8;        // +64 per kt; +sub*16*Ss per sub

    for (int kt = 0; kt <= qt; ++kt) {
        // scores S = Q K^T (log2 units); K B-frags straight from L2
        f32x4 s[4];
        __builtin_amdgcn_s_setprio(1);
#pragma unroll
        for (int sub = 0; sub < 4; ++sub) {
            s[sub] = (f32x4){0,0,0,0};
            f16x8 kf0 = *(const f16x8*)(kp + (size_t)sub * 16 * Ee);
            s[sub] = __builtin_amdgcn_mfma_f32_16x16x32_f16(qf0, kf0, s[sub], 0, 0, 0);
            f16x8 kf1 = *(const f16x8*)(kp + (size_t)sub * 16 * Ee + 32);
            s[sub] = __builtin_amdgcn_mfma_f32_16x16x32_f16(qf1, kf1, s[sub], 0, 0, 0);
        }
        __builtin_amdgcn_s_setprio(0);
        if (kt == qt) {  // causal mask on the diagonal tile (k0 == q0)
#pragma unroll
            for (int sub = 0; sub < 4; ++sub)
#pragma unroll
                for (int r = 0; r < 4; ++r)
                    if (sub * 16 + ar > wave * 16 + kg * 4 + r) s[sub][r] = -1e30f;
        }
        // online softmax (row = kg*4+r, col = ar; reduce over 16 lanes)
#pragma unroll
        for (int r = 0; r < 4; ++r) {
            float mt = fmaxf(fmaxf(s[0][r], s[1][r]), fmaxf(s[2][r], s[3][r]));
            mt = fmaxf(mt, __shfl_xor(mt, 1));
            mt = fmaxf(mt, __shfl_xor(mt, 2));
            mt = fmaxf(mt, __shfl_xor(mt, 4));
            mt = fmaxf(mt, __shfl_xor(mt, 8));
            float mn = fmaxf(m[r], mt);
            float sc = exp2_fast(m[r] - mn);
            float rs = 0.f;
#pragma unroll
            for (int sub = 0; sub < 4; ++sub) {
                float p = exp2_fast(s[sub][r] - mn);
                rs += p;
                Pl[wave][kg * 4 + r][sub * 16 + ar] = (half_t)p;
            }
            rs += __shfl_xor(rs, 1);
            rs += __shfl_xor(rs, 2);
            rs += __shfl_xor(rs, 4);
            rs += __shfl_xor(rs, 8);
            l[r] = l[r] * sc + rs;
            m[r] = mn;
            o[0][r] *= sc; o[1][r] *= sc; o[2][r] *= sc; o[3][r] *= sc;
        }
        // PV: o += P[16x64] * V[64x64]; V^T B-frags straight from L2
        f16x8 pf0 = *(const f16x8*)&Pl[wave][ar][kg * 8];
        f16x8 pf1 = *(const f16x8*)&Pl[wave][ar][32 + kg * 8];
        __builtin_amdgcn_s_setprio(1);
#pragma unroll
        for (int sub = 0; sub < 4; ++sub) {
            const half_t* vp = vpb + (size_t)sub * 16 * Ss;
            f16x8 vf0 = *(const f16x8*)vp;
            o[sub] = __builtin_amdgcn_mfma_f32_16x16x32_f16(pf0, vf0, o[sub], 0, 0, 0);
            f16x8 vf1 = *(const f16x8*)(vp + 32);
            o[sub] = __builtin_amdgcn_mfma_f32_16x16x32_f16(pf1, vf1, o[sub], 0, 0, 0);
        }
        __builtin_amdgcn_s_setprio(0);
        kp  += 64 * Ee;
        vpb += 64;
    }
    // epilogue: ctx[b, s, h*E + e] f16 (head-major concat)
    int b = bh >> 3, h = bh & 7;
#pragma unroll
    for (int sub = 0; sub < 4; ++sub)
#pragma unroll
        for (int r = 0; r < 4; ++r) {
            int row = q0 + wave * 16 + kg * 4 + r;
            ctx[((size_t)b * Ss + row) * Ff + h * Ee + sub * 16 + ar] = (half_t)(o[sub][r] / l[r]);
        }
}

// ---------------- output projection: ctx[16384,512] x WoT -> out f32 ----------------
// grid (M/64, O/64) = (256, 8)
__global__ __launch_bounds__(256) void k_proj(const half_t* __restrict__ ctx,
                                              const half_t* __restrict__ WoT,
                                              float* __restrict__ out) {
    int mt = blockIdx.x, ot = blockIdx.y;
    int wave = threadIdx.x >> 6, lane = threadIdx.x & 63;
    int ar = lane & 15, kg = lane >> 4;

    const half_t* arow = ctx + ((size_t)mt * 64 + wave * 16 + ar) * Ff + kg * 8;
    const half_t* brow = WoT + ((size_t)ot * 64 + ar) * Ff + kg * 8;

    f32x4 acc[4];
#pragma unroll
    for (int i = 0; i < 4; ++i) acc[i] = (f32x4){0,0,0,0};

    for (int k0 = 0; k0 < Ff; k0 += 32) {
        f16x8 a = *(const f16x8*)(arow + k0);
#pragma unroll
        for (int sub = 0; sub < 4; ++sub) {
            f16x8 b = *(const f16x8*)(brow + (size_t)sub * 16 * Ff + k0);
            acc[sub] = __builtin_amdgcn_mfma_f32_16x16x32_f16(a, b, acc[sub], 0, 0, 0);
        }
    }
#pragma unroll
    for (int sub = 0; sub < 4; ++sub)
#pragma unroll
        for (int r = 0; r < 4; ++r)
            out[((size_t)mt * 64 + wave * 16 + kg * 4 + r) * Oo + ot * 64 + sub * 16 + ar] = acc[sub][r];
}

extern "C" void kernel_launch(void* const* d_in, const int* in_sizes, int n_in,
                              void* d_out, int out_size, void* d_ws, size_t ws_size,
                              hipStream_t stream) {
    const float* x  = (const float*)d_in[0];
    const float* Wq = (const float*)d_in[1];
    const float* Wk = (const float*)d_in[2];
    const float* Wv = (const float*)d_in[3];
    const float* Wo = (const float*)d_in[4];
    float* out = (float*)d_out;

    // workspace layout (all f16, fully rewritten every call): ~86 MB
    char* ws = (char*)d_ws;
    size_t off = 0;
    half_t* xh  = (half_t*)(ws + off); off += (size_t)Bb * Ss * Dd * 2;   // 16 MB
    half_t* WqT = (half_t*)(ws + off); off += (size_t)Hh * Ee * Dd * 2;
    half_t* WkT = (half_t*)(ws + off); off += (size_t)Hh * Ee * Dd * 2;
    half_t* WvT = (half_t*)(ws + off); off += (size_t)Hh * Ee * Dd * 2;
    half_t* WoT = (half_t*)(ws + off); off += (size_t)Ff * Oo * 2;
    half_t* Qd  = (half_t*)(ws + off); off += (size_t)Bb * Hh * Ss * Ee * 2;
    half_t* Kd  = (half_t*)(ws + off); off += (size_t)Bb * Hh * Ss * Ee * 2;
    half_t* Vtd = (half_t*)(ws + off); off += (size_t)Bb * Hh * Ss * Ee * 2;  // transposed [bh][e][s]
    half_t* ctx = (half_t*)(ws + off); off += (size_t)Bb * Ss * Ff * 2;

    k_cvt_x<<<8192, 256, 0, stream>>>(x, xh);
    k_cvt_w<<<1024, 256, 0, stream>>>(Wq, Wk, Wv, Wo, WqT, WkT, WvT, WoT);
    k_qkv<<<dim3(Ss / 64, Bb * Hh), 256, 0, stream>>>(xh, WqT, WkT, WvT, Qd, Kd, Vtd);
    k_attn<<<2048, 256, 0, stream>>>(Qd, Kd, Vtd, ctx);
    k_proj<<<dim3((Bb * Ss) / 64, Oo / 64), 256, 0, stream>>>(ctx, WoT, out);
}

// Round 6
// 526.617 us; speedup vs baseline: 1.0935x; 1.0699x over previous
//
#include <hip/hip_runtime.h>
#include <stdint.h>

// Problem constants
#define Bb 8
#define Ss 2048
#define Dd 512
#define Hh 8
#define Ee 64
#define Oo 512
#define Ff 512   // H*E

typedef _Float16 half_t;
typedef __attribute__((ext_vector_type(8))) _Float16 f16x8;  // 8 fp16 (4 VGPRs)
typedef __attribute__((ext_vector_type(4))) float f32x4;     // MFMA acc
typedef __attribute__((ext_vector_type(4))) float f4;
typedef __attribute__((ext_vector_type(4))) half_t h16x4;

__device__ __forceinline__ float exp2_fast(float x) {
    float r; asm("v_exp_f32 %0, %1" : "=v"(r) : "v"(x)); return r;  // HW 2^x
}

// ---------------- query f32 -> f16 ----------------
__global__ __launch_bounds__(256) void k_cvt_x(const float* __restrict__ x,
                                               half_t* __restrict__ xh) {
    size_t i = ((size_t)blockIdx.x * 256 + threadIdx.x) * 4;
    f4 v = *(const f4*)(x + i);
    h16x4 o;
    o[0] = (half_t)v[0]; o[1] = (half_t)v[1]; o[2] = (half_t)v[2]; o[3] = (half_t)v[3];
    *(h16x4*)(xh + i) = o;
}

// -------- weights: Wq/Wk/Wv [H,D,E] -> f16 [H,E,D]; Wo [F,O] -> f16 [O,F] --------
__global__ __launch_bounds__(256) void k_cvt_w(const float* __restrict__ Wq, const float* __restrict__ Wk,
                                               const float* __restrict__ Wv, const float* __restrict__ Wo,
                                               half_t* __restrict__ WqT, half_t* __restrict__ WkT,
                                               half_t* __restrict__ WvT, half_t* __restrict__ WoT) {
    int t = blockIdx.x * 256 + threadIdx.x;            // 0 .. H*D*E-1 (== F*O-1)
    int h = t / (Dd * Ee); int rem = t - h * (Dd * Ee);
    int d = rem / Ee;      int e = rem - d * Ee;
    int ti = (h * Ee + e) * Dd + d;
    WqT[ti] = (half_t)Wq[t];
    WkT[ti] = (half_t)Wk[t];
    WvT[ti] = (half_t)Wv[t];
    int f = t / Oo; int o = t - f * Oo;
    WoT[o * Ff + f] = (half_t)Wo[t];
}

// ---------------- fused QKV projection (register-pipelined) ----------------
// grid (S/64, B*H), 256 thr (4 waves x 16 rows). Per wave: 16x64 out, K=512.
// Loads for step k0+32 issue right after step k0's MFMAs consume the regs (WAR rotation).
// V is written TRANSPOSED: Vt[bh][e][s]
__global__ __launch_bounds__(256, 4) void k_qkv(const half_t* __restrict__ xh,
                                                const half_t* __restrict__ WqT,
                                                const half_t* __restrict__ WkT,
                                                const half_t* __restrict__ WvT,
                                                half_t* __restrict__ Q,
                                                half_t* __restrict__ K,
                                                half_t* __restrict__ Vt) {
    int st = blockIdx.x, bh = blockIdx.y;
    int b = bh >> 3, h = bh & 7;
    int wave = threadIdx.x >> 6, lane = threadIdx.x & 63;
    int ar = lane & 15, kg = lane >> 4;

    const half_t* xr  = xh + ((size_t)b * Ss + st * 64 + wave * 16 + ar) * Dd + kg * 8;
    const half_t* wqb = WqT + (size_t)h * Ee * Dd + (size_t)ar * Dd + kg * 8;
    const half_t* wkb = WkT + (size_t)h * Ee * Dd + (size_t)ar * Dd + kg * 8;
    const half_t* wvb = WvT + (size_t)h * Ee * Dd + (size_t)ar * Dd + kg * 8;

    f32x4 aq[4], ak[4], av[4];
#pragma unroll
    for (int i = 0; i < 4; ++i) { aq[i] = (f32x4){0,0,0,0}; ak[i] = (f32x4){0,0,0,0}; av[i] = (f32x4){0,0,0,0}; }

    // preload step 0
    f16x8 a = *(const f16x8*)xr;
    f16x8 bq[4], bk[4], bv[4];
#pragma unroll
    for (int sub = 0; sub < 4; ++sub) {
        bq[sub] = *(const f16x8*)(wqb + (size_t)sub * 16 * Dd);
        bk[sub] = *(const f16x8*)(wkb + (size_t)sub * 16 * Dd);
        bv[sub] = *(const f16x8*)(wvb + (size_t)sub * 16 * Dd);
    }

    for (int k0 = 0; k0 < Dd; k0 += 32) {
        __builtin_amdgcn_s_setprio(1);
#pragma unroll
        for (int sub = 0; sub < 4; ++sub) {
            aq[sub] = __builtin_amdgcn_mfma_f32_16x16x32_f16(a, bq[sub], aq[sub], 0, 0, 0);
            ak[sub] = __builtin_amdgcn_mfma_f32_16x16x32_f16(a, bk[sub], ak[sub], 0, 0, 0);
            av[sub] = __builtin_amdgcn_mfma_f32_16x16x32_f16(a, bv[sub], av[sub], 0, 0, 0);
        }
        __builtin_amdgcn_s_setprio(0);
        int k0n = (k0 + 32 < Dd) ? k0 + 32 : k0;   // clamped (last iter re-loads, harmless)
        a = *(const f16x8*)(xr + k0n);
#pragma unroll
        for (int sub = 0; sub < 4; ++sub) {
            bq[sub] = *(const f16x8*)(wqb + (size_t)sub * 16 * Dd + k0n);
            bk[sub] = *(const f16x8*)(wkb + (size_t)sub * 16 * Dd + k0n);
            bv[sub] = *(const f16x8*)(wvb + (size_t)sub * 16 * Dd + k0n);
        }
    }
    // C/D layout: col = lane&15, row = (lane>>4)*4 + r   [measured m89]
    size_t obase = ((size_t)bh * Ss + st * 64 + wave * 16) * Ee;
#pragma unroll
    for (int sub = 0; sub < 4; ++sub)
#pragma unroll
        for (int r = 0; r < 4; ++r) {
            int s_loc = st * 64 + wave * 16 + kg * 4 + r;
            size_t oi = obase + (size_t)(kg * 4 + r) * Ee + sub * 16 + ar;
            Q[oi] = (half_t)aq[sub][r];
            K[oi] = (half_t)ak[sub][r];
            Vt[((size_t)bh * Ee + sub * 16 + ar) * Ss + s_loc] = (half_t)av[sub][r];
        }
}

// ---------------- flash-style causal attention (barrier-free, reg-pipelined) ----------------
// 2048 one-D blocks; decode: xcd = bid&7 owns heads [xcd*8, xcd*8+8) -> K/V L2-resident.
// qt descending (longest-first). Each block: ONE q-tile x ONE head; 4 waves x 16 q-rows.
// K/V frags rotated one tile ahead in registers (loads fly during softmax / next QK).
// Deferred l-reduction: per-lane partial lp, one shuffle-reduce at epilogue.
__global__ __launch_bounds__(256, 3) void k_attn(const half_t* __restrict__ Q,
                                                 const half_t* __restrict__ Kg,
                                                 const half_t* __restrict__ Vtg,
                                                 half_t* __restrict__ ctx) {
    __shared__ __attribute__((aligned(16))) half_t Pl[4][16][72];   // per-wave P tile [q][k]

    int bid = blockIdx.x;                 // 0..2047
    int xcd = bid & 7;
    int idx = bid >> 3;                   // 0..255
    int qt  = 31 - (idx >> 3);            // 31..0 (longest first)
    int bh  = xcd * 8 + (idx & 7);        // head 0..63, 8 heads per XCD

    int wave = threadIdx.x >> 6, lane = threadIdx.x & 63;
    int ar = lane & 15, kg = lane >> 4;
    int q0 = qt * 64;

    const half_t* Qb = Q   + (size_t)bh * Ss * Ee;
    const half_t* Kb = Kg  + (size_t)bh * Ss * Ee;
    const half_t* Vb = Vtg + (size_t)bh * Ee * Ss;

    // Q A-frags, pre-scaled by log2(e) so softmax runs in exp2 domain
    const half_t* qp = Qb + (size_t)(q0 + wave * 16 + ar) * Ee + kg * 8;
    f16x8 qf0 = *(const f16x8*)qp;
    f16x8 qf1 = *(const f16x8*)(qp + 32);
    const half_t l2e = (half_t)1.44269504f;
#pragma unroll
    for (int j = 0; j < 8; ++j) { qf0[j] *= l2e; qf1[j] *= l2e; }

    f32x4 o[4]; float m[4], lp[4];
#pragma unroll
    for (int i = 0; i < 4; ++i) { o[i] = (f32x4){0,0,0,0}; m[i] = -1e30f; lp[i] = 0.f; }

    const half_t* kp0 = Kb + (size_t)ar * Ee + kg * 8;   // tile-0 lane base
    const half_t* vp0 = Vb + (size_t)ar * Ss + kg * 8;

    // preload K/V tile 0
    f16x8 kf[8], vf[8];
#pragma unroll
    for (int sub = 0; sub < 4; ++sub) {
        kf[2 * sub]     = *(const f16x8*)(kp0 + (size_t)sub * 16 * Ee);
        kf[2 * sub + 1] = *(const f16x8*)(kp0 + (size_t)sub * 16 * Ee + 32);
        vf[2 * sub]     = *(const f16x8*)(vp0 + (size_t)sub * 16 * Ss);
        vf[2 * sub + 1] = *(const f16x8*)(vp0 + (size_t)sub * 16 * Ss + 32);
    }

    for (int kt = 0; kt <= qt; ++kt) {
        // ---- QK^T from resident K frags ----
        f32x4 s[4];
        __builtin_amdgcn_s_setprio(1);
#pragma unroll
        for (int sub = 0; sub < 4; ++sub) {
            s[sub] = (f32x4){0,0,0,0};
            s[sub] = __builtin_amdgcn_mfma_f32_16x16x32_f16(qf0, kf[2 * sub], s[sub], 0, 0, 0);
            s[sub] = __builtin_amdgcn_mfma_f32_16x16x32_f16(qf1, kf[2 * sub + 1], s[sub], 0, 0, 0);
        }
        __builtin_amdgcn_s_setprio(0);
        // ---- prefetch K tile kt+1 (clamped); lands during softmax+PV ----
        int ktn = kt + (kt < qt);
        const half_t* kpn = Kb + (size_t)ktn * 64 * Ee + (size_t)ar * Ee + kg * 8;
#pragma unroll
        for (int sub = 0; sub < 4; ++sub) {
            kf[2 * sub]     = *(const f16x8*)(kpn + (size_t)sub * 16 * Ee);
            kf[2 * sub + 1] = *(const f16x8*)(kpn + (size_t)sub * 16 * Ee + 32);
        }
        if (kt == qt) {  // causal mask on the diagonal tile
#pragma unroll
            for (int sub = 0; sub < 4; ++sub)
#pragma unroll
                for (int r = 0; r < 4; ++r)
                    if (sub * 16 + ar > wave * 16 + kg * 4 + r) s[sub][r] = -1e30f;
        }
        // ---- online softmax (deferred l; 4 shuffles per row, max only) ----
#pragma unroll
        for (int r = 0; r < 4; ++r) {
            float mt = fmaxf(fmaxf(s[0][r], s[1][r]), fmaxf(s[2][r], s[3][r]));
            mt = fmaxf(mt, __shfl_xor(mt, 1));
            mt = fmaxf(mt, __shfl_xor(mt, 2));
            mt = fmaxf(mt, __shfl_xor(mt, 4));
            mt = fmaxf(mt, __shfl_xor(mt, 8));
            float mn = fmaxf(m[r], mt);
            float sc = exp2_fast(m[r] - mn);
            float rs = 0.f;
#pragma unroll
            for (int sub = 0; sub < 4; ++sub) {
                float p = exp2_fast(s[sub][r] - mn);
                rs += p;
                Pl[wave][kg * 4 + r][sub * 16 + ar] = (half_t)p;
            }
            lp[r] = lp[r] * sc + rs;       // per-lane partial; reduced at epilogue
            m[r] = mn;
            o[0][r] *= sc; o[1][r] *= sc; o[2][r] *= sc; o[3][r] *= sc;
        }
        // ---- PV from resident V frags ----
        f16x8 pf0 = *(const f16x8*)&Pl[wave][ar][kg * 8];
        f16x8 pf1 = *(const f16x8*)&Pl[wave][ar][32 + kg * 8];
        __builtin_amdgcn_s_setprio(1);
#pragma unroll
        for (int sub = 0; sub < 4; ++sub) {
            o[sub] = __builtin_amdgcn_mfma_f32_16x16x32_f16(pf0, vf[2 * sub], o[sub], 0, 0, 0);
            o[sub] = __builtin_amdgcn_mfma_f32_16x16x32_f16(pf1, vf[2 * sub + 1], o[sub], 0, 0, 0);
        }
        __builtin_amdgcn_s_setprio(0);
        // ---- prefetch V tile kt+1 (clamped); lands during next QK+softmax ----
        const half_t* vpn = Vb + (size_t)ktn * 64 + (size_t)ar * Ss + kg * 8;
#pragma unroll
        for (int sub = 0; sub < 4; ++sub) {
            vf[2 * sub]     = *(const f16x8*)(vpn + (size_t)sub * 16 * Ss);
            vf[2 * sub + 1] = *(const f16x8*)(vpn + (size_t)sub * 16 * Ss + 32);
        }
    }
    // final l reduction (per 16-lane row group)
    float lf[4];
#pragma unroll
    for (int r = 0; r < 4; ++r) {
        float t = lp[r];
        t += __shfl_xor(t, 1);
        t += __shfl_xor(t, 2);
        t += __shfl_xor(t, 4);
        t += __shfl_xor(t, 8);
        lf[r] = t;
    }
    // epilogue: ctx[b, s, h*E + e] f16 (head-major concat)
    int b = bh >> 3, h = bh & 7;
#pragma unroll
    for (int sub = 0; sub < 4; ++sub)
#pragma unroll
        for (int r = 0; r < 4; ++r) {
            int row = q0 + wave * 16 + kg * 4 + r;
            ctx[((size_t)b * Ss + row) * Ff + h * Ee + sub * 16 + ar] = (half_t)(o[sub][r] / lf[r]);
        }
}

// ---------------- output projection: ctx[16384,512] x WoT -> out f32 (reg-pipelined) ----
// grid (M/64, O/64) = (256, 8)
__global__ __launch_bounds__(256, 6) void k_proj(const half_t* __restrict__ ctx,
                                                 const half_t* __restrict__ WoT,
                                                 float* __restrict__ out) {
    int mt = blockIdx.x, ot = blockIdx.y;
    int wave = threadIdx.x >> 6, lane = threadIdx.x & 63;
    int ar = lane & 15, kg = lane >> 4;

    const half_t* arow = ctx + ((size_t)mt * 64 + wave * 16 + ar) * Ff + kg * 8;
    const half_t* brow = WoT + ((size_t)ot * 64 + ar) * Ff + kg * 8;

    f32x4 acc[4];
#pragma unroll
    for (int i = 0; i < 4; ++i) acc[i] = (f32x4){0,0,0,0};

    f16x8 a = *(const f16x8*)arow;
    f16x8 bb[4];
#pragma unroll
    for (int sub = 0; sub < 4; ++sub) bb[sub] = *(const f16x8*)(brow + (size_t)sub * 16 * Ff);

    for (int k0 = 0; k0 < Ff; k0 += 32) {
        __builtin_amdgcn_s_setprio(1);
#pragma unroll
        for (int sub = 0; sub < 4; ++sub)
            acc[sub] = __builtin_amdgcn_mfma_f32_16x16x32_f16(a, bb[sub], acc[sub], 0, 0, 0);
        __builtin_amdgcn_s_setprio(0);
        int k0n = (k0 + 32 < Ff) ? k0 + 32 : k0;
        a = *(const f16x8*)(arow + k0n);
#pragma unroll
        for (int sub = 0; sub < 4; ++sub)
            bb[sub] = *(const f16x8*)(brow + (size_t)sub * 16 * Ff + k0n);
    }
#pragma unroll
    for (int sub = 0; sub < 4; ++sub)
#pragma unroll
        for (int r = 0; r < 4; ++r)
            out[((size_t)mt * 64 + wave * 16 + kg * 4 + r) * Oo + ot * 64 + sub * 16 + ar] = acc[sub][r];
}

extern "C" void kernel_launch(void* const* d_in, const int* in_sizes, int n_in,
                              void* d_out, int out_size, void* d_ws, size_t ws_size,
                              hipStream_t stream) {
    const float* x  = (const float*)d_in[0];
    const float* Wq = (const float*)d_in[1];
    const float* Wk = (const float*)d_in[2];
    const float* Wv = (const float*)d_in[3];
    const float* Wo = (const float*)d_in[4];
    float* out = (float*)d_out;

    // workspace layout (all f16, fully rewritten every call): ~86 MB
    char* ws = (char*)d_ws;
    size_t off = 0;
    half_t* xh  = (half_t*)(ws + off); off += (size_t)Bb * Ss * Dd * 2;   // 16 MB
    half_t* WqT = (half_t*)(ws + off); off += (size_t)Hh * Ee * Dd * 2;
    half_t* WkT = (half_t*)(ws + off); off += (size_t)Hh * Ee * Dd * 2;
    half_t* WvT = (half_t*)(ws + off); off += (size_t)Hh * Ee * Dd * 2;
    half_t* WoT = (half_t*)(ws + off); off += (size_t)Ff * Oo * 2;
    half_t* Qd  = (half_t*)(ws + off); off += (size_t)Bb * Hh * Ss * Ee * 2;
    half_t* Kd  = (half_t*)(ws + off); off += (size_t)Bb * Hh * Ss * Ee * 2;
    half_t* Vtd = (half_t*)(ws + off); off += (size_t)Bb * Hh * Ss * Ee * 2;  // transposed [bh][e][s]
    half_t* ctx = (half_t*)(ws + off); off += (size_t)Bb * Ss * Ff * 2;

    k_cvt_x<<<8192, 256, 0, stream>>>(x, xh);
    k_cvt_w<<<1024, 256, 0, stream>>>(Wq, Wk, Wv, Wo, WqT, WkT, WvT, WoT);
    k_qkv<<<dim3(Ss / 64, Bb * Hh), 256, 0, stream>>>(xh, WqT, WkT, WvT, Qd, Kd, Vtd);
    k_attn<<<2048, 256, 0, stream>>>(Qd, Kd, Vtd, ctx);
    k_proj<<<dim3((Bb * Ss) / 64, Oo / 64), 256, 0, stream>>>(ctx, WoT, out);
}

// Round 7
// 427.916 us; speedup vs baseline: 1.3457x; 1.2307x over previous
//
#include <hip/hip_runtime.h>
#include <stdint.h>

// Problem constants
#define Bb 8
#define Ss 2048
#define Dd 512
#define Hh 8
#define Ee 64
#define Oo 512
#define Ff 512   // H*E

typedef _Float16 half_t;
typedef __attribute__((ext_vector_type(8))) _Float16 f16x8;   // 8 fp16 (4 VGPRs)
typedef __attribute__((ext_vector_type(4))) float f32x4;      // 16x16 MFMA acc
typedef __attribute__((ext_vector_type(16))) float f32x16;    // 32x32 MFMA acc
typedef __attribute__((ext_vector_type(4))) float f4;
typedef __attribute__((ext_vector_type(4))) half_t h16x4;

__device__ __forceinline__ float exp2_fast(float x) {
    float r; asm("v_exp_f32 %0, %1" : "=v"(r) : "v"(x)); return r;  // HW 2^x
}
__device__ __forceinline__ f32x16 zero16() {
    f32x16 z;
#pragma unroll
    for (int i = 0; i < 16; ++i) z[i] = 0.f;
    return z;
}

// ---------------- query f32 -> f16 ----------------
__global__ __launch_bounds__(256) void k_cvt_x(const float* __restrict__ x,
                                               half_t* __restrict__ xh) {
    size_t i = ((size_t)blockIdx.x * 256 + threadIdx.x) * 4;
    f4 v = *(const f4*)(x + i);
    h16x4 o;
    o[0] = (half_t)v[0]; o[1] = (half_t)v[1]; o[2] = (half_t)v[2]; o[3] = (half_t)v[3];
    *(h16x4*)(xh + i) = o;
}

// -------- weights: Wq/Wk/Wv [H,D,E] -> f16 [H,E,D]; Wo [F,O] -> f16 [O,F] --------
__global__ __launch_bounds__(256) void k_cvt_w(const float* __restrict__ Wq, const float* __restrict__ Wk,
                                               const float* __restrict__ Wv, const float* __restrict__ Wo,
                                               half_t* __restrict__ WqT, half_t* __restrict__ WkT,
                                               half_t* __restrict__ WvT, half_t* __restrict__ WoT) {
    int t = blockIdx.x * 256 + threadIdx.x;            // 0 .. H*D*E-1 (== F*O-1)
    int h = t / (Dd * Ee); int rem = t - h * (Dd * Ee);
    int d = rem / Ee;      int e = rem - d * Ee;
    int ti = (h * Ee + e) * Dd + d;
    WqT[ti] = (half_t)Wq[t];
    WkT[ti] = (half_t)Wk[t];
    WvT[ti] = (half_t)Wv[t];
    int f = t / Oo; int o = t - f * Oo;
    WoT[o * Ff + f] = (half_t)Wo[t];
}

// ---------------- fused QKV projection (register-pipelined) ----------------
// grid (S/64, B*H), 256 thr (4 waves x 16 rows). Per wave: 16x64 out, K=512.
// V is written TRANSPOSED: Vt[bh][e][s]
__global__ __launch_bounds__(256, 4) void k_qkv(const half_t* __restrict__ xh,
                                                const half_t* __restrict__ WqT,
                                                const half_t* __restrict__ WkT,
                                                const half_t* __restrict__ WvT,
                                                half_t* __restrict__ Q,
                                                half_t* __restrict__ K,
                                                half_t* __restrict__ Vt) {
    int st = blockIdx.x, bh = blockIdx.y;
    int b = bh >> 3, h = bh & 7;
    int wave = threadIdx.x >> 6, lane = threadIdx.x & 63;
    int ar = lane & 15, kg = lane >> 4;

    const half_t* xr  = xh + ((size_t)b * Ss + st * 64 + wave * 16 + ar) * Dd + kg * 8;
    const half_t* wqb = WqT + (size_t)h * Ee * Dd + (size_t)ar * Dd + kg * 8;
    const half_t* wkb = WkT + (size_t)h * Ee * Dd + (size_t)ar * Dd + kg * 8;
    const half_t* wvb = WvT + (size_t)h * Ee * Dd + (size_t)ar * Dd + kg * 8;

    f32x4 aq[4], ak[4], av[4];
#pragma unroll
    for (int i = 0; i < 4; ++i) { aq[i] = (f32x4){0,0,0,0}; ak[i] = (f32x4){0,0,0,0}; av[i] = (f32x4){0,0,0,0}; }

    f16x8 a = *(const f16x8*)xr;
    f16x8 bq[4], bk[4], bv[4];
#pragma unroll
    for (int sub = 0; sub < 4; ++sub) {
        bq[sub] = *(const f16x8*)(wqb + (size_t)sub * 16 * Dd);
        bk[sub] = *(const f16x8*)(wkb + (size_t)sub * 16 * Dd);
        bv[sub] = *(const f16x8*)(wvb + (size_t)sub * 16 * Dd);
    }

    for (int k0 = 0; k0 < Dd; k0 += 32) {
        __builtin_amdgcn_s_setprio(1);
#pragma unroll
        for (int sub = 0; sub < 4; ++sub) {
            aq[sub] = __builtin_amdgcn_mfma_f32_16x16x32_f16(a, bq[sub], aq[sub], 0, 0, 0);
            ak[sub] = __builtin_amdgcn_mfma_f32_16x16x32_f16(a, bk[sub], ak[sub], 0, 0, 0);
            av[sub] = __builtin_amdgcn_mfma_f32_16x16x32_f16(a, bv[sub], av[sub], 0, 0, 0);
        }
        __builtin_amdgcn_s_setprio(0);
        int k0n = (k0 + 32 < Dd) ? k0 + 32 : k0;
        a = *(const f16x8*)(xr + k0n);
#pragma unroll
        for (int sub = 0; sub < 4; ++sub) {
            bq[sub] = *(const f16x8*)(wqb + (size_t)sub * 16 * Dd + k0n);
            bk[sub] = *(const f16x8*)(wkb + (size_t)sub * 16 * Dd + k0n);
            bv[sub] = *(const f16x8*)(wvb + (size_t)sub * 16 * Dd + k0n);
        }
    }
    size_t obase = ((size_t)bh * Ss + st * 64 + wave * 16) * Ee;
#pragma unroll
    for (int sub = 0; sub < 4; ++sub)
#pragma unroll
        for (int r = 0; r < 4; ++r) {
            int s_loc = st * 64 + wave * 16 + kg * 4 + r;
            size_t oi = obase + (size_t)(kg * 4 + r) * Ee + sub * 16 + ar;
            Q[oi] = (half_t)aq[sub][r];
            K[oi] = (half_t)ak[sub][r];
            Vt[((size_t)bh * Ee + sub * 16 + ar) * Ss + s_loc] = (half_t)av[sub][r];
        }
}

// ---------------- flash attention: swapped-operand 32x32, in-register softmax ----------------
// 1024 blocks (xcd=bid&7 owns 8 heads -> K/V ~L2-resident), longest-first.
// Block = 4 waves; wave w owns q-tile-32 qt32 = qb*4+w. ZERO LDS; no barriers.
// QK^T: mfma(A=K, B=Q) -> lane owns q=lane&31, 16 k-scores in regs (k = (r&3)+8*(r>>2)+4*hi).
// Softmax per-lane; P packed to f16 via v_cvt_pkrtz + 4 xor-32 shuffles.
// PV: O^T[e][q] = mfma(A=V^T frag, B=P frag) -> output col q = lane&31 (same domain).
__global__ __launch_bounds__(256, 3) void k_attn(const half_t* __restrict__ Q,
                                                 const half_t* __restrict__ Kg,
                                                 const half_t* __restrict__ Vtg,
                                                 half_t* __restrict__ ctx) {
    int bid = blockIdx.x;                 // 0..1023
    int xcd = bid & 7;
    int idx = bid >> 3;                   // 0..127
    int qb  = 15 - (idx >> 3);            // q-block of 128 rows, longest first
    int bh  = xcd * 8 + (idx & 7);        // 8 heads per XCD

    int wave = threadIdx.x >> 6, lane = threadIdx.x & 63;
    int ql = lane & 31, hi = lane >> 5;
    int qt32 = qb * 4 + wave;             // this wave's 32-row q-tile
    int qg = qt32 * 32 + ql;              // this lane's q row (global)

    const half_t* Qb = Q   + (size_t)bh * Ss * Ee;
    const half_t* Kb = Kg  + (size_t)bh * Ss * Ee;
    const half_t* Vb = Vtg + (size_t)bh * Ee * Ss;

    // Q B-frags (persistent): Q[qg][d*16 + hi*8 + j], pre-scaled by log2(e)
    const half_t* qp = Qb + (size_t)qg * Ee + hi * 8;
    f16x8 qf[4];
    const half_t l2e = (half_t)1.44269504f;
#pragma unroll
    for (int d = 0; d < 4; ++d) {
        qf[d] = *(const f16x8*)(qp + d * 16);
#pragma unroll
        for (int j = 0; j < 8; ++j) qf[d][j] *= l2e;
    }

    f32x16 ot0 = zero16(), ot1 = zero16();
    float m = -1e30f, lp = 0.f;

    const half_t* vrow0 = Vb + (size_t)ql * Ss + hi * 8;          // e = ql
    const half_t* vrow1 = vrow0 + (size_t)32 * Ss;                // e = 32+ql

    // preload K tile 0: K[kt*32+ql][d*16 + hi*8 + j]
    const half_t* kp0 = Kb + (size_t)ql * Ee + hi * 8;
    f16x8 kf0 = *(const f16x8*)(kp0);
    f16x8 kf1 = *(const f16x8*)(kp0 + 16);
    f16x8 kf2 = *(const f16x8*)(kp0 + 32);
    f16x8 kf3 = *(const f16x8*)(kp0 + 48);

    for (int kt = 0; kt <= qt32; ++kt) {
        // V^T A-frags for this tile (fly during QK + softmax)
        f16x8 va00 = *(const f16x8*)(vrow0 + kt * 32);
        f16x8 va01 = *(const f16x8*)(vrow0 + kt * 32 + 16);
        f16x8 va10 = *(const f16x8*)(vrow1 + kt * 32);
        f16x8 va11 = *(const f16x8*)(vrow1 + kt * 32 + 16);

        // S'[k][q] = K Q^T (log2 domain)
        f32x16 s = zero16();
        __builtin_amdgcn_s_setprio(1);
        s = __builtin_amdgcn_mfma_f32_32x32x16_f16(kf0, qf[0], s, 0, 0, 0);
        s = __builtin_amdgcn_mfma_f32_32x32x16_f16(kf1, qf[1], s, 0, 0, 0);
        s = __builtin_amdgcn_mfma_f32_32x32x16_f16(kf2, qf[2], s, 0, 0, 0);
        s = __builtin_amdgcn_mfma_f32_32x32x16_f16(kf3, qf[3], s, 0, 0, 0);
        __builtin_amdgcn_s_setprio(0);

        // prefetch next K tile (clamped; WAR after QK consumed kf)
        {
            int ktn = (kt < qt32) ? kt + 1 : kt;
            const half_t* kpn = Kb + ((size_t)ktn * 32 + ql) * Ee + hi * 8;
            kf0 = *(const f16x8*)(kpn);
            kf1 = *(const f16x8*)(kpn + 16);
            kf2 = *(const f16x8*)(kpn + 32);
            kf3 = *(const f16x8*)(kpn + 48);
        }

        if (kt == qt32) {  // causal mask on the diagonal tile: mask k_loc > q_loc
#pragma unroll
            for (int r = 0; r < 16; ++r) {
                int kloc = (r & 3) + 8 * (r >> 2) + 4 * hi;
                if (kloc > ql) s[r] = -1e30f;
            }
        }

        // per-lane softmax over 32 k (own 16 + partner half via one xor-32)
        float mt = s[0];
#pragma unroll
        for (int r = 1; r < 16; ++r) mt = fmaxf(mt, s[r]);
        mt = fmaxf(mt, __shfl_xor(mt, 32));
        if (!__all(mt <= m + 8.0f)) {      // T13 defer-max: rescale only on real growth
            float mn = fmaxf(m, mt);
            float sc = exp2_fast(m - mn);
#pragma unroll
            for (int r = 0; r < 16; ++r) { ot0[r] *= sc; ot1[r] *= sc; }
            lp *= sc;
            m = mn;
        }
        float rs = 0.f;
#pragma unroll
        for (int r = 0; r < 16; ++r) { s[r] = exp2_fast(s[r] - m); rs += s[r]; }
        lp += rs;

        // pack P to f16 pairs; build PV B-frags with 4 xor-32 shuffles
        unsigned w[8];
#pragma unroll
        for (int mm = 0; mm < 8; ++mm)
            asm("v_cvt_pkrtz_f16_f32 %0, %1, %2" : "=v"(w[mm]) : "v"(s[2 * mm]), "v"(s[2 * mm + 1]));
        unsigned t0 = (unsigned)__shfl_xor((int)(hi ? w[0] : w[2]), 32);
        unsigned t1 = (unsigned)__shfl_xor((int)(hi ? w[1] : w[3]), 32);
        unsigned t2 = (unsigned)__shfl_xor((int)(hi ? w[4] : w[6]), 32);
        unsigned t3 = (unsigned)__shfl_xor((int)(hi ? w[5] : w[7]), 32);
        union { unsigned u[4]; f16x8 v; } pb0, pb1;
        pb0.u[0] = hi ? t0 : w[0];  pb0.u[1] = hi ? t1 : w[1];
        pb0.u[2] = hi ? w[2] : t0;  pb0.u[3] = hi ? w[3] : t1;
        pb1.u[0] = hi ? t2 : w[4];  pb1.u[1] = hi ? t3 : w[5];
        pb1.u[2] = hi ? w[6] : t2;  pb1.u[3] = hi ? w[7] : t3;

        // O^T += V^T P  (col q = lane&31)
        __builtin_amdgcn_s_setprio(1);
        ot0 = __builtin_amdgcn_mfma_f32_32x32x16_f16(va00, pb0.v, ot0, 0, 0, 0);
        ot0 = __builtin_amdgcn_mfma_f32_32x32x16_f16(va01, pb1.v, ot0, 0, 0, 0);
        ot1 = __builtin_amdgcn_mfma_f32_32x32x16_f16(va10, pb0.v, ot1, 0, 0, 0);
        ot1 = __builtin_amdgcn_mfma_f32_32x32x16_f16(va11, pb1.v, ot1, 0, 0, 0);
        __builtin_amdgcn_s_setprio(0);
    }

    // final l (combine partner half), normalize, store
    float lf = lp + __shfl_xor(lp, 32);
    float inv = 1.0f / lf;
    int b = bh >> 3, h = bh & 7;
    half_t* cb = ctx + ((size_t)b * Ss + qg) * Ff + h * Ee;
#pragma unroll
    for (int g = 0; g < 4; ++g) {
        h16x4 v0, v1;
#pragma unroll
        for (int j = 0; j < 4; ++j) {
            v0[j] = (half_t)(ot0[g * 4 + j] * inv);
            v1[j] = (half_t)(ot1[g * 4 + j] * inv);
        }
        int e = 8 * g + 4 * hi;           // row = (r&3) + 8*(r>>2) + 4*hi
        *(h16x4*)(cb + e)      = v0;      // e-block 0..31
        *(h16x4*)(cb + 32 + e) = v1;      // e-block 32..63
    }
}

// ---------------- output projection: ctx[16384,512] x WoT -> out f32 (reg-pipelined) ----
// grid (M/64, O/64) = (256, 8)
__global__ __launch_bounds__(256, 6) void k_proj(const half_t* __restrict__ ctx,
                                                 const half_t* __restrict__ WoT,
                                                 float* __restrict__ out) {
    int mt = blockIdx.x, ot = blockIdx.y;
    int wave = threadIdx.x >> 6, lane = threadIdx.x & 63;
    int ar = lane & 15, kg = lane >> 4;

    const half_t* arow = ctx + ((size_t)mt * 64 + wave * 16 + ar) * Ff + kg * 8;
    const half_t* brow = WoT + ((size_t)ot * 64 + ar) * Ff + kg * 8;

    f32x4 acc[4];
#pragma unroll
    for (int i = 0; i < 4; ++i) acc[i] = (f32x4){0,0,0,0};

    f16x8 a = *(const f16x8*)arow;
    f16x8 bb[4];
#pragma unroll
    for (int sub = 0; sub < 4; ++sub) bb[sub] = *(const f16x8*)(brow + (size_t)sub * 16 * Ff);

    for (int k0 = 0; k0 < Ff; k0 += 32) {
        __builtin_amdgcn_s_setprio(1);
#pragma unroll
        for (int sub = 0; sub < 4; ++sub)
            acc[sub] = __builtin_amdgcn_mfma_f32_16x16x32_f16(a, bb[sub], acc[sub], 0, 0, 0);
        __builtin_amdgcn_s_setprio(0);
        int k0n = (k0 + 32 < Ff) ? k0 + 32 : k0;
        a = *(const f16x8*)(arow + k0n);
#pragma unroll
        for (int sub = 0; sub < 4; ++sub)
            bb[sub] = *(const f16x8*)(brow + (size_t)sub * 16 * Ff + k0n);
    }
#pragma unroll
    for (int sub = 0; sub < 4; ++sub)
#pragma unroll
        for (int r = 0; r < 4; ++r)
            out[((size_t)mt * 64 + wave * 16 + kg * 4 + r) * Oo + ot * 64 + sub * 16 + ar] = acc[sub][r];
}

extern "C" void kernel_launch(void* const* d_in, const int* in_sizes, int n_in,
                              void* d_out, int out_size, void* d_ws, size_t ws_size,
                              hipStream_t stream) {
    const float* x  = (const float*)d_in[0];
    const float* Wq = (const float*)d_in[1];
    const float* Wk = (const float*)d_in[2];
    const float* Wv = (const float*)d_in[3];
    const float* Wo = (const float*)d_in[4];
    float* out = (float*)d_out;

    // workspace layout (all f16, fully rewritten every call): ~86 MB
    char* ws = (char*)d_ws;
    size_t off = 0;
    half_t* xh  = (half_t*)(ws + off); off += (size_t)Bb * Ss * Dd * 2;   // 16 MB
    half_t* WqT = (half_t*)(ws + off); off += (size_t)Hh * Ee * Dd * 2;
    half_t* WkT = (half_t*)(ws + off); off += (size_t)Hh * Ee * Dd * 2;
    half_t* WvT = (half_t*)(ws + off); off += (size_t)Hh * Ee * Dd * 2;
    half_t* WoT = (half_t*)(ws + off); off += (size_t)Ff * Oo * 2;
    half_t* Qd  = (half_t*)(ws + off); off += (size_t)Bb * Hh * Ss * Ee * 2;
    half_t* Kd  = (half_t*)(ws + off); off += (size_t)Bb * Hh * Ss * Ee * 2;
    half_t* Vtd = (half_t*)(ws + off); off += (size_t)Bb * Hh * Ss * Ee * 2;  // transposed [bh][e][s]
    half_t* ctx = (half_t*)(ws + off); off += (size_t)Bb * Ss * Ff * 2;

    k_cvt_x<<<8192, 256, 0, stream>>>(x, xh);
    k_cvt_w<<<1024, 256, 0, stream>>>(Wq, Wk, Wv, Wo, WqT, WkT, WvT, WoT);
    k_qkv<<<dim3(Ss / 64, Bb * Hh), 256, 0, stream>>>(xh, WqT, WkT, WvT, Qd, Kd, Vtd);
    k_attn<<<1024, 256, 0, stream>>>(Qd, Kd, Vtd, ctx);
    k_proj<<<dim3((Bb * Ss) / 64, Oo / 64), 256, 0, stream>>>(ctx, WoT, out);
}

// Round 8
// 232.396 us; speedup vs baseline: 2.4778x; 1.8413x over previous
//
#include <hip/hip_runtime.h>
#include <stdint.h>

// Problem constants
#define Bb 8
#define Ss 2048
#define Dd 512
#define Hh 8
#define Ee 64
#define Oo 512
#define Ff 512    // H*E
#define Ncat 1536 // 3*H*E fused QKV output columns

typedef _Float16 half_t;
typedef __attribute__((ext_vector_type(8))) _Float16 f16x8;   // 8 fp16 (4 VGPRs)
typedef __attribute__((ext_vector_type(4))) float f32x4;      // 16x16 MFMA acc
typedef __attribute__((ext_vector_type(16))) float f32x16;    // 32x32 MFMA acc
typedef __attribute__((ext_vector_type(4))) float f4;
typedef __attribute__((ext_vector_type(4))) half_t h16x4;
typedef __attribute__((ext_vector_type(4))) unsigned int u32x4;

__device__ __forceinline__ float exp2_fast(float x) {
    float r; asm("v_exp_f32 %0, %1" : "=v"(r) : "v"(x)); return r;  // HW 2^x
}
__device__ __forceinline__ f32x16 zero16() {
    f32x16 z;
#pragma unroll
    for (int i = 0; i < 16; ++i) z[i] = 0.f;
    return z;
}
// async global->LDS, 16B per lane; LDS dest is wave-uniform base + lane*16 (HW)
__device__ __forceinline__ void gload16(const half_t* g, half_t* l) {
    __builtin_amdgcn_global_load_lds(
        (const __attribute__((address_space(1))) void*)g,
        (__attribute__((address_space(3))) void*)l, 16, 0, 0);
}

// ---------------- query f32 -> f16, chunk-swizzled (c ^= s&7 within 64-el groups) -----
// one 8-el chunk per thread; 16384 rows x 64 chunks
__global__ __launch_bounds__(256) void k_cvt_x(const float* __restrict__ x,
                                               half_t* __restrict__ xh) {
    int t = blockIdx.x * 256 + threadIdx.x;
    int s = t >> 6, c = t & 63;
    int cg = c >> 3, cl = c & 7;
    const float* src = x + (size_t)s * Dd + c * 8;
    f4 v0 = *(const f4*)src;
    f4 v1 = *(const f4*)(src + 4);
    union { half_t h[8]; u32x4 u; } o;
#pragma unroll
    for (int j = 0; j < 4; ++j) { o.h[j] = (half_t)v0[j]; o.h[4 + j] = (half_t)v1[j]; }
    int cd = cg * 8 + (cl ^ (s & 7));
    *(u32x4*)(xh + (size_t)s * Dd + cd * 8) = o.u;
}

// -------- weights: Wcat[n][d] (n = sel*512 + h*64 + e), WoT[o][f]; both chunk-swizzled --
__global__ __launch_bounds__(256) void k_cvt_w(const float* __restrict__ Wq, const float* __restrict__ Wk,
                                               const float* __restrict__ Wv, const float* __restrict__ Wo,
                                               half_t* __restrict__ Wcat, half_t* __restrict__ WoT) {
    int t = blockIdx.x * 256 + threadIdx.x;            // 0 .. 131071
    union { half_t h[8]; u32x4 u; } o;
    if (t < Ncat * 64) {                               // Wcat: n-row chunks
        int n = t >> 6, dc = t & 63;
        int sel = n >> 9, h = (n >> 6) & 7, e = n & 63;
        const float* W = (sel == 0) ? Wq : (sel == 1) ? Wk : Wv;
        const float* src = W + ((size_t)h * Dd + dc * 8) * Ee + e;   // W[h][d][e], stride Ee over d
#pragma unroll
        for (int j = 0; j < 8; ++j) o.h[j] = (half_t)src[(size_t)j * Ee];
        int dcs = (dc & ~7) | ((dc & 7) ^ (n & 7));
        *(u32x4*)(Wcat + (size_t)n * Dd + dcs * 8) = o.u;
    } else {                                           // WoT: o-row chunks
        int u2 = t - Ncat * 64;
        int oo = u2 >> 6, fc = u2 & 63;
        const float* src = Wo + (size_t)(fc * 8) * Oo + oo;          // Wo[f][o], stride Oo over f
#pragma unroll
        for (int j = 0; j < 8; ++j) o.h[j] = (half_t)src[(size_t)j * Oo];
        int fcs = (fc & ~7) | ((fc & 7) ^ (oo & 7));
        *(u32x4*)(WoT + (size_t)oo * Ff + fcs * 8) = o.u;
    }
}

// ---------------- fused QKV: one GEMM C[16384,1536] = X * Wcat^T (2-phase gload_lds) ----
// 1536 blocks (XCD-chunked remap), 128x128 tile, BK=64, 4 waves (2x2), 64x64 out/wave.
__global__ __launch_bounds__(256, 2) void k_qkv(const half_t* __restrict__ A,    // xh (swizzled)
                                                const half_t* __restrict__ Bw,   // Wcat (swizzled)
                                                half_t* __restrict__ Q,
                                                half_t* __restrict__ K,
                                                half_t* __restrict__ Vt) {
    __shared__ __attribute__((aligned(16))) half_t Ab[2][128 * 64];
    __shared__ __attribute__((aligned(16))) half_t Bbuf[2][128 * 64];

    int bid = blockIdx.x;
    int virt = (bid & 7) * 192 + (bid >> 3);           // XCD x owns virt [x*192, x*192+192)
    int bm = virt / 12, bn = virt % 12;
    int m0 = bm * 128, n0 = bn * 128;

    int wave = threadIdx.x >> 6, lane = threadIdx.x & 63;
    int ar = lane & 15, kg = lane >> 4;
    int wm = wave >> 1, wn = wave & 1;
    int lr = lane >> 3, lc = lane & 7;                 // staging: row-in-seg, chunk

    f32x4 acc[4][4];
#pragma unroll
    for (int i = 0; i < 4; ++i)
#pragma unroll
        for (int j = 0; j < 4; ++j) acc[i][j] = (f32x4){0, 0, 0, 0};

#define STAGE_QKV(buf, kt)                                                              \
    {                                                                                   \
        _Pragma("unroll")                                                               \
        for (int i = 0; i < 4; ++i) {                                                   \
            int seg = wave * 4 + i;                                                     \
            int row = seg * 8 + lr;                                                     \
            gload16(A  + (size_t)(m0 + row) * Dd + (kt) * 64 + lc * 8, &Ab[buf][seg * 512]);   \
            gload16(Bw + (size_t)(n0 + row) * Dd + (kt) * 64 + lc * 8, &Bbuf[buf][seg * 512]); \
        }                                                                               \
    }

    STAGE_QKV(0, 0);
    __syncthreads();
    int cur = 0;
    for (int kt = 0; kt < 8; ++kt) {
        if (kt < 7) STAGE_QKV(cur ^ 1, kt + 1);
        f16x8 bf[4][2];
#pragma unroll
        for (int n = 0; n < 4; ++n) {
            int row = wn * 64 + n * 16 + ar;
#pragma unroll
            for (int kh = 0; kh < 2; ++kh)
                bf[n][kh] = *(const f16x8*)&Bbuf[cur][row * 64 + (((kg + kh * 4)) ^ (row & 7)) * 8];
        }
#pragma unroll
        for (int mi = 0; mi < 4; ++mi) {
            int row = wm * 64 + mi * 16 + ar;
            f16x8 a0 = *(const f16x8*)&Ab[cur][row * 64 + ((kg)     ^ (row & 7)) * 8];
            f16x8 a1 = *(const f16x8*)&Ab[cur][row * 64 + ((kg + 4) ^ (row & 7)) * 8];
#pragma unroll
            for (int n = 0; n < 4; ++n) {
                acc[mi][n] = __builtin_amdgcn_mfma_f32_16x16x32_f16(a0, bf[n][0], acc[mi][n], 0, 0, 0);
                acc[mi][n] = __builtin_amdgcn_mfma_f32_16x16x32_f16(a1, bf[n][1], acc[mi][n], 0, 0, 0);
            }
        }
        __syncthreads();
        cur ^= 1;
    }
    // epilogue: sel is block-uniform (N tiled 4/4/4 over Q,K,V)
    int sel = n0 >> 9;
#pragma unroll
    for (int sn = 0; sn < 4; ++sn) {
        int nb = n0 + wn * 64 + sn * 16;
        int h = (nb >> 6) & 7, eb = nb & 63;
#pragma unroll
        for (int mi = 0; mi < 4; ++mi)
#pragma unroll
            for (int r = 0; r < 4; ++r) {
                int sg = m0 + wm * 64 + mi * 16 + kg * 4 + r;
                int bh = (sg >> 11) * 8 + h, sl = sg & 2047;
                half_t val = (half_t)acc[mi][sn][r];
                if (sel == 0)      Q [((size_t)bh * Ss + sl) * Ee + eb + ar] = val;
                else if (sel == 1) K [((size_t)bh * Ss + sl) * Ee + eb + ar] = val;
                else               Vt[((size_t)bh * Ee + eb + ar) * Ss + sl] = val;
            }
    }
#undef STAGE_QKV
}

// ---------------- flash attention: swapped-operand 32x32, in-register softmax ----------
// (unchanged from R7 except ctx stores are chunk-swizzled for the proj GEMM)
__global__ __launch_bounds__(256, 3) void k_attn(const half_t* __restrict__ Q,
                                                 const half_t* __restrict__ Kg,
                                                 const half_t* __restrict__ Vtg,
                                                 half_t* __restrict__ ctx) {
    int bid = blockIdx.x;                 // 0..1023
    int xcd = bid & 7;
    int idx = bid >> 3;                   // 0..127
    int qb  = 15 - (idx >> 3);            // q-block of 128 rows, longest first
    int bh  = xcd * 8 + (idx & 7);        // 8 heads per XCD

    int wave = threadIdx.x >> 6, lane = threadIdx.x & 63;
    int ql = lane & 31, hi = lane >> 5;
    int qt32 = qb * 4 + wave;
    int qg = qt32 * 32 + ql;

    const half_t* Qb = Q   + (size_t)bh * Ss * Ee;
    const half_t* Kb = Kg  + (size_t)bh * Ss * Ee;
    const half_t* Vb = Vtg + (size_t)bh * Ee * Ss;

    const half_t* qp = Qb + (size_t)qg * Ee + hi * 8;
    f16x8 qf[4];
    const half_t l2e = (half_t)1.44269504f;
#pragma unroll
    for (int d = 0; d < 4; ++d) {
        qf[d] = *(const f16x8*)(qp + d * 16);
#pragma unroll
        for (int j = 0; j < 8; ++j) qf[d][j] *= l2e;
    }

    f32x16 ot0 = zero16(), ot1 = zero16();
    float m = -1e30f, lp = 0.f;

    const half_t* vrow0 = Vb + (size_t)ql * Ss + hi * 8;
    const half_t* vrow1 = vrow0 + (size_t)32 * Ss;

    const half_t* kp0 = Kb + (size_t)ql * Ee + hi * 8;
    f16x8 kf0 = *(const f16x8*)(kp0);
    f16x8 kf1 = *(const f16x8*)(kp0 + 16);
    f16x8 kf2 = *(const f16x8*)(kp0 + 32);
    f16x8 kf3 = *(const f16x8*)(kp0 + 48);

    for (int kt = 0; kt <= qt32; ++kt) {
        f16x8 va00 = *(const f16x8*)(vrow0 + kt * 32);
        f16x8 va01 = *(const f16x8*)(vrow0 + kt * 32 + 16);
        f16x8 va10 = *(const f16x8*)(vrow1 + kt * 32);
        f16x8 va11 = *(const f16x8*)(vrow1 + kt * 32 + 16);

        f32x16 s = zero16();
        __builtin_amdgcn_s_setprio(1);
        s = __builtin_amdgcn_mfma_f32_32x32x16_f16(kf0, qf[0], s, 0, 0, 0);
        s = __builtin_amdgcn_mfma_f32_32x32x16_f16(kf1, qf[1], s, 0, 0, 0);
        s = __builtin_amdgcn_mfma_f32_32x32x16_f16(kf2, qf[2], s, 0, 0, 0);
        s = __builtin_amdgcn_mfma_f32_32x32x16_f16(kf3, qf[3], s, 0, 0, 0);
        __builtin_amdgcn_s_setprio(0);

        {
            int ktn = (kt < qt32) ? kt + 1 : kt;
            const half_t* kpn = Kb + ((size_t)ktn * 32 + ql) * Ee + hi * 8;
            kf0 = *(const f16x8*)(kpn);
            kf1 = *(const f16x8*)(kpn + 16);
            kf2 = *(const f16x8*)(kpn + 32);
            kf3 = *(const f16x8*)(kpn + 48);
        }

        if (kt == qt32) {
#pragma unroll
            for (int r = 0; r < 16; ++r) {
                int kloc = (r & 3) + 8 * (r >> 2) + 4 * hi;
                if (kloc > ql) s[r] = -1e30f;
            }
        }

        float mt = s[0];
#pragma unroll
        for (int r = 1; r < 16; ++r) mt = fmaxf(mt, s[r]);
        mt = fmaxf(mt, __shfl_xor(mt, 32));
        if (!__all(mt <= m + 8.0f)) {
            float mn = fmaxf(m, mt);
            float sc = exp2_fast(m - mn);
#pragma unroll
            for (int r = 0; r < 16; ++r) { ot0[r] *= sc; ot1[r] *= sc; }
            lp *= sc;
            m = mn;
        }
        float rs = 0.f;
#pragma unroll
        for (int r = 0; r < 16; ++r) { s[r] = exp2_fast(s[r] - m); rs += s[r]; }
        lp += rs;

        unsigned w[8];
#pragma unroll
        for (int mm = 0; mm < 8; ++mm)
            asm("v_cvt_pkrtz_f16_f32 %0, %1, %2" : "=v"(w[mm]) : "v"(s[2 * mm]), "v"(s[2 * mm + 1]));
        unsigned t0 = (unsigned)__shfl_xor((int)(hi ? w[0] : w[2]), 32);
        unsigned t1 = (unsigned)__shfl_xor((int)(hi ? w[1] : w[3]), 32);
        unsigned t2 = (unsigned)__shfl_xor((int)(hi ? w[4] : w[6]), 32);
        unsigned t3 = (unsigned)__shfl_xor((int)(hi ? w[5] : w[7]), 32);
        union { unsigned u[4]; f16x8 v; } pb0, pb1;
        pb0.u[0] = hi ? t0 : w[0];  pb0.u[1] = hi ? t1 : w[1];
        pb0.u[2] = hi ? w[2] : t0;  pb0.u[3] = hi ? w[3] : t1;
        pb1.u[0] = hi ? t2 : w[4];  pb1.u[1] = hi ? t3 : w[5];
        pb1.u[2] = hi ? w[6] : t2;  pb1.u[3] = hi ? w[7] : t3;

        __builtin_amdgcn_s_setprio(1);
        ot0 = __builtin_amdgcn_mfma_f32_32x32x16_f16(va00, pb0.v, ot0, 0, 0, 0);
        ot0 = __builtin_amdgcn_mfma_f32_32x32x16_f16(va01, pb1.v, ot0, 0, 0, 0);
        ot1 = __builtin_amdgcn_mfma_f32_32x32x16_f16(va10, pb0.v, ot1, 0, 0, 0);
        ot1 = __builtin_amdgcn_mfma_f32_32x32x16_f16(va11, pb1.v, ot1, 0, 0, 0);
        __builtin_amdgcn_s_setprio(0);
    }

    float lf = lp + __shfl_xor(lp, 32);
    float inv = 1.0f / lf;
    int b = bh >> 3, h = bh & 7;
    int qs = qg & 7;
    half_t* cb = ctx + ((size_t)b * Ss + qg) * Ff;
#pragma unroll
    for (int g = 0; g < 4; ++g) {
        h16x4 v0, v1;
#pragma unroll
        for (int j = 0; j < 4; ++j) {
            v0[j] = (half_t)(ot0[g * 4 + j] * inv);
            v1[j] = (half_t)(ot1[g * 4 + j] * inv);
        }
        // plain f = h*64 + 8g + 4hi (+32); chunk-swizzle c^=qs within 8-chunk group
        *(h16x4*)(cb + (h * 8 + (g ^ qs)) * 8 + 4 * hi)       = v0;
        *(h16x4*)(cb + (h * 8 + ((g + 4) ^ qs)) * 8 + 4 * hi) = v1;
    }
}

// ---------------- output projection: same 2-phase GEMM, C[16384,512] f32 ----------------
__global__ __launch_bounds__(256, 2) void k_proj(const half_t* __restrict__ A,    // ctx (swizzled)
                                                 const half_t* __restrict__ Bw,   // WoT (swizzled)
                                                 float* __restrict__ out) {
    __shared__ __attribute__((aligned(16))) half_t Ab[2][128 * 64];
    __shared__ __attribute__((aligned(16))) half_t Bbuf[2][128 * 64];

    int bid = blockIdx.x;
    int virt = (bid & 7) * 64 + (bid >> 3);
    int bm = virt >> 2, bn = virt & 3;
    int m0 = bm * 128, n0 = bn * 128;

    int wave = threadIdx.x >> 6, lane = threadIdx.x & 63;
    int ar = lane & 15, kg = lane >> 4;
    int wm = wave >> 1, wn = wave & 1;
    int lr = lane >> 3, lc = lane & 7;

    f32x4 acc[4][4];
#pragma unroll
    for (int i = 0; i < 4; ++i)
#pragma unroll
        for (int j = 0; j < 4; ++j) acc[i][j] = (f32x4){0, 0, 0, 0};

#define STAGE_PRJ(buf, kt)                                                              \
    {                                                                                   \
        _Pragma("unroll")                                                               \
        for (int i = 0; i < 4; ++i) {                                                   \
            int seg = wave * 4 + i;                                                     \
            int row = seg * 8 + lr;                                                     \
            gload16(A  + (size_t)(m0 + row) * Ff + (kt) * 64 + lc * 8, &Ab[buf][seg * 512]);   \
            gload16(Bw + (size_t)(n0 + row) * Ff + (kt) * 64 + lc * 8, &Bbuf[buf][seg * 512]); \
        }                                                                               \
    }

    STAGE_PRJ(0, 0);
    __syncthreads();
    int cur = 0;
    for (int kt = 0; kt < 8; ++kt) {
        if (kt < 7) STAGE_PRJ(cur ^ 1, kt + 1);
        f16x8 bf[4][2];
#pragma unroll
        for (int n = 0; n < 4; ++n) {
            int row = wn * 64 + n * 16 + ar;
#pragma unroll
            for (int kh = 0; kh < 2; ++kh)
                bf[n][kh] = *(const f16x8*)&Bbuf[cur][row * 64 + (((kg + kh * 4)) ^ (row & 7)) * 8];
        }
#pragma unroll
        for (int mi = 0; mi < 4; ++mi) {
            int row = wm * 64 + mi * 16 + ar;
            f16x8 a0 = *(const f16x8*)&Ab[cur][row * 64 + ((kg)     ^ (row & 7)) * 8];
            f16x8 a1 = *(const f16x8*)&Ab[cur][row * 64 + ((kg + 4) ^ (row & 7)) * 8];
#pragma unroll
            for (int n = 0; n < 4; ++n) {
                acc[mi][n] = __builtin_amdgcn_mfma_f32_16x16x32_f16(a0, bf[n][0], acc[mi][n], 0, 0, 0);
                acc[mi][n] = __builtin_amdgcn_mfma_f32_16x16x32_f16(a1, bf[n][1], acc[mi][n], 0, 0, 0);
            }
        }
        __syncthreads();
        cur ^= 1;
    }
#pragma unroll
    for (int sn = 0; sn < 4; ++sn)
#pragma unroll
        for (int mi = 0; mi < 4; ++mi)
#pragma unroll
            for (int r = 0; r < 4; ++r) {
                int sg = m0 + wm * 64 + mi * 16 + kg * 4 + r;
                out[(size_t)sg * Oo + n0 + wn * 64 + sn * 16 + ar] = acc[mi][sn][r];
            }
#undef STAGE_PRJ
}

extern "C" void kernel_launch(void* const* d_in, const int* in_sizes, int n_in,
                              void* d_out, int out_size, void* d_ws, size_t ws_size,
                              hipStream_t stream) {
    const float* x  = (const float*)d_in[0];
    const float* Wq = (const float*)d_in[1];
    const float* Wk = (const float*)d_in[2];
    const float* Wv = (const float*)d_in[3];
    const float* Wo = (const float*)d_in[4];
    float* out = (float*)d_out;

    // workspace (all f16, fully rewritten every call): ~82 MB
    char* ws = (char*)d_ws;
    size_t off = 0;
    half_t* xh   = (half_t*)(ws + off); off += (size_t)Bb * Ss * Dd * 2;      // swizzled
    half_t* Wcat = (half_t*)(ws + off); off += (size_t)Ncat * Dd * 2;         // swizzled
    half_t* WoT  = (half_t*)(ws + off); off += (size_t)Oo * Ff * 2;           // swizzled
    half_t* Qd   = (half_t*)(ws + off); off += (size_t)Bb * Hh * Ss * Ee * 2; // plain [bh][s][e]
    half_t* Kd   = (half_t*)(ws + off); off += (size_t)Bb * Hh * Ss * Ee * 2; // plain [bh][s][e]
    half_t* Vtd  = (half_t*)(ws + off); off += (size_t)Bb * Hh * Ss * Ee * 2; // plain [bh][e][s]
    half_t* ctx  = (half_t*)(ws + off); off += (size_t)Bb * Ss * Ff * 2;      // swizzled

    k_cvt_x<<<4096, 256, 0, stream>>>(x, xh);
    k_cvt_w<<<512, 256, 0, stream>>>(Wq, Wk, Wv, Wo, Wcat, WoT);
    k_qkv<<<1536, 256, 0, stream>>>(xh, Wcat, Qd, Kd, Vtd);
    k_attn<<<1024, 256, 0, stream>>>(Qd, Kd, Vtd, ctx);
    k_proj<<<512, 256, 0, stream>>>(ctx, WoT, out);
}

// Round 9
// 155.755 us; speedup vs baseline: 3.6971x; 1.4921x over previous
//
#include <hip/hip_runtime.h>
#include <stdint.h>

// Problem constants
#define Bb 8
#define Ss 2048
#define Dd 512
#define Hh 8
#define Ee 64
#define Oo 512
#define Ff 512    // H*E
#define Ncat 1536 // 3*H*E fused QKV output columns

typedef _Float16 half_t;
typedef __attribute__((ext_vector_type(8))) _Float16 f16x8;   // 8 fp16 (4 VGPRs)
typedef __attribute__((ext_vector_type(4))) float f32x4;      // 16x16 MFMA acc
typedef __attribute__((ext_vector_type(16))) float f32x16;    // 32x32 MFMA acc
typedef __attribute__((ext_vector_type(4))) float f4;
typedef __attribute__((ext_vector_type(4))) half_t h16x4;
typedef __attribute__((ext_vector_type(4))) unsigned int u32x4;

__device__ __forceinline__ float exp2_fast(float x) {
    float r; asm("v_exp_f32 %0, %1" : "=v"(r) : "v"(x)); return r;  // HW 2^x
}
__device__ __forceinline__ f32x16 zero16() {
    f32x16 z;
#pragma unroll
    for (int i = 0; i < 16; ++i) z[i] = 0.f;
    return z;
}
// async global->LDS, 16B per lane; LDS dest is wave-uniform base + lane*16 (HW)
__device__ __forceinline__ void gload16(const half_t* g, half_t* l) {
    __builtin_amdgcn_global_load_lds(
        (const __attribute__((address_space(1))) void*)g,
        (__attribute__((address_space(3))) void*)l, 16, 0, 0);
}

// ---------------- query f32 -> f16, chunk-swizzled (c ^= s&7 within 64-el groups) -----
__global__ __launch_bounds__(256) void k_cvt_x(const float* __restrict__ x,
                                               half_t* __restrict__ xh) {
    int t = blockIdx.x * 256 + threadIdx.x;
    int s = t >> 6, c = t & 63;
    int cg = c >> 3, cl = c & 7;
    const float* src = x + (size_t)s * Dd + c * 8;
    f4 v0 = *(const f4*)src;
    f4 v1 = *(const f4*)(src + 4);
    union { half_t h[8]; u32x4 u; } o;
#pragma unroll
    for (int j = 0; j < 4; ++j) { o.h[j] = (half_t)v0[j]; o.h[4 + j] = (half_t)v1[j]; }
    int cd = cg * 8 + (cl ^ (s & 7));
    *(u32x4*)(xh + (size_t)s * Dd + cd * 8) = o.u;
}

// -------- weights: Wcat[n][d] (n = sel*512 + h*64 + e), WoT[o][f]; both chunk-swizzled --
__global__ __launch_bounds__(256) void k_cvt_w(const float* __restrict__ Wq, const float* __restrict__ Wk,
                                               const float* __restrict__ Wv, const float* __restrict__ Wo,
                                               half_t* __restrict__ Wcat, half_t* __restrict__ WoT) {
    int t = blockIdx.x * 256 + threadIdx.x;            // 0 .. 131071
    union { half_t h[8]; u32x4 u; } o;
    if (t < Ncat * 64) {                               // Wcat: n-row chunks
        int n = t >> 6, dc = t & 63;
        int sel = n >> 9, h = (n >> 6) & 7, e = n & 63;
        const float* W = (sel == 0) ? Wq : (sel == 1) ? Wk : Wv;
        const float* src = W + ((size_t)h * Dd + dc * 8) * Ee + e;   // W[h][d][e], stride Ee over d
#pragma unroll
        for (int j = 0; j < 8; ++j) o.h[j] = (half_t)src[(size_t)j * Ee];
        int dcs = (dc & ~7) | ((dc & 7) ^ (n & 7));
        *(u32x4*)(Wcat + (size_t)n * Dd + dcs * 8) = o.u;
    } else {                                           // WoT: o-row chunks
        int u2 = t - Ncat * 64;
        int oo = u2 >> 6, fc = u2 & 63;
        const float* src = Wo + (size_t)(fc * 8) * Oo + oo;          // Wo[f][o], stride Oo over f
#pragma unroll
        for (int j = 0; j < 8; ++j) o.h[j] = (half_t)src[(size_t)j * Oo];
        int fcs = (fc & ~7) | ((fc & 7) ^ (oo & 7));
        *(u32x4*)(WoT + (size_t)oo * Ff + fcs * 8) = o.u;
    }
}

// ---------------- fused QKV: one GEMM C[16384,1536] = X * Wcat^T (2-phase gload_lds) ----
__global__ __launch_bounds__(256, 2) void k_qkv(const half_t* __restrict__ A,    // xh (swizzled)
                                                const half_t* __restrict__ Bw,   // Wcat (swizzled)
                                                half_t* __restrict__ Q,
                                                half_t* __restrict__ K,
                                                half_t* __restrict__ Vt) {
    __shared__ __attribute__((aligned(16))) half_t Ab[2][128 * 64];
    __shared__ __attribute__((aligned(16))) half_t Bbuf[2][128 * 64];

    int bid = blockIdx.x;
    int virt = (bid & 7) * 192 + (bid >> 3);           // XCD x owns virt [x*192, x*192+192)
    int bm = virt / 12, bn = virt % 12;
    int m0 = bm * 128, n0 = bn * 128;

    int wave = threadIdx.x >> 6, lane = threadIdx.x & 63;
    int ar = lane & 15, kg = lane >> 4;
    int wm = wave >> 1, wn = wave & 1;
    int lr = lane >> 3, lc = lane & 7;                 // staging: row-in-seg, chunk

    f32x4 acc[4][4];
#pragma unroll
    for (int i = 0; i < 4; ++i)
#pragma unroll
        for (int j = 0; j < 4; ++j) acc[i][j] = (f32x4){0, 0, 0, 0};

#define STAGE_QKV(buf, kt)                                                              \
    {                                                                                   \
        _Pragma("unroll")                                                               \
        for (int i = 0; i < 4; ++i) {                                                   \
            int seg = wave * 4 + i;                                                     \
            int row = seg * 8 + lr;                                                     \
            gload16(A  + (size_t)(m0 + row) * Dd + (kt) * 64 + lc * 8, &Ab[buf][seg * 512]);   \
            gload16(Bw + (size_t)(n0 + row) * Dd + (kt) * 64 + lc * 8, &Bbuf[buf][seg * 512]); \
        }                                                                               \
    }

    STAGE_QKV(0, 0);
    __syncthreads();
    int cur = 0;
    for (int kt = 0; kt < 8; ++kt) {
        if (kt < 7) STAGE_QKV(cur ^ 1, kt + 1);
        f16x8 bf[4][2];
#pragma unroll
        for (int n = 0; n < 4; ++n) {
            int row = wn * 64 + n * 16 + ar;
#pragma unroll
            for (int kh = 0; kh < 2; ++kh)
                bf[n][kh] = *(const f16x8*)&Bbuf[cur][row * 64 + (((kg + kh * 4)) ^ (row & 7)) * 8];
        }
#pragma unroll
        for (int mi = 0; mi < 4; ++mi) {
            int row = wm * 64 + mi * 16 + ar;
            f16x8 a0 = *(const f16x8*)&Ab[cur][row * 64 + ((kg)     ^ (row & 7)) * 8];
            f16x8 a1 = *(const f16x8*)&Ab[cur][row * 64 + ((kg + 4) ^ (row & 7)) * 8];
#pragma unroll
            for (int n = 0; n < 4; ++n) {
                acc[mi][n] = __builtin_amdgcn_mfma_f32_16x16x32_f16(a0, bf[n][0], acc[mi][n], 0, 0, 0);
                acc[mi][n] = __builtin_amdgcn_mfma_f32_16x16x32_f16(a1, bf[n][1], acc[mi][n], 0, 0, 0);
            }
        }
        __syncthreads();
        cur ^= 1;
    }
    // epilogue: sel is block-uniform (N tiled 4/4/4 over Q,K,V)
    int sel = n0 >> 9;
#pragma unroll
    for (int sn = 0; sn < 4; ++sn) {
        int nb = n0 + wn * 64 + sn * 16;
        int h = (nb >> 6) & 7, eb = nb & 63;
#pragma unroll
        for (int mi = 0; mi < 4; ++mi)
#pragma unroll
            for (int r = 0; r < 4; ++r) {
                int sg = m0 + wm * 64 + mi * 16 + kg * 4 + r;
                int bh = (sg >> 11) * 8 + h, sl = sg & 2047;
                half_t val = (half_t)acc[mi][sn][r];
                if (sel == 0)      Q [((size_t)bh * Ss + sl) * Ee + eb + ar] = val;
                else if (sel == 1) K [((size_t)bh * Ss + sl) * Ee + eb + ar] = val;
                else               Vt[((size_t)bh * Ee + eb + ar) * Ss + sl] = val;
            }
    }
#undef STAGE_QKV
}

// ---------------- flash attention: swapped 32x32 + block-shared K/V LDS staging --------
// 1024 blocks (xcd=bid&7 owns 8 heads), longest-first. Block = 4 waves on CONSECUTIVE
// q-tiles (qb*4+w) of the SAME head -> common kt loop (<=3 wasted tiles), K/V staged
// ONCE per block per tile via global_load_lds (double-buffered, 1 barrier/iter).
// K LDS[r][c16] holds Kglob[r][c^ (r&7)]; V LDS[e][c16] holds Vt[e][c ^ (e&3)] (rule 21).
__global__ __launch_bounds__(256, 3) void k_attn(const half_t* __restrict__ Q,
                                                 const half_t* __restrict__ Kg,
                                                 const half_t* __restrict__ Vtg,
                                                 half_t* __restrict__ ctx) {
    __shared__ __attribute__((aligned(16))) half_t Klds[2][32 * 64];   // [k=32][e=64]
    __shared__ __attribute__((aligned(16))) half_t Vlds[2][64 * 32];   // [e=64][k=32]

    int bid = blockIdx.x;                 // 0..1023
    int xcd = bid & 7;
    int idx = bid >> 3;                   // 0..127
    int qb  = 15 - (idx >> 3);            // q-block of 128 rows, longest first
    int bh  = xcd * 8 + (idx & 7);        // 8 heads per XCD

    int wave = threadIdx.x >> 6, lane = threadIdx.x & 63;
    int ql = lane & 31, hi = lane >> 5;
    int qt32 = qb * 4 + wave;             // this wave's 32-row q-tile
    int ktmax = qb * 4 + 3;               // block-common staging range
    int qg = qt32 * 32 + ql;

    const half_t* Qb = Q   + (size_t)bh * Ss * Ee;
    const half_t* Kb = Kg  + (size_t)bh * Ss * Ee;
    const half_t* Vb = Vtg + (size_t)bh * Ee * Ss;

    // Q B-frags (persistent), pre-scaled by log2(e)
    const half_t* qp = Qb + (size_t)qg * Ee + hi * 8;
    f16x8 qf[4];
    const half_t l2e = (half_t)1.44269504f;
#pragma unroll
    for (int d = 0; d < 4; ++d) {
        qf[d] = *(const f16x8*)(qp + d * 16);
#pragma unroll
        for (int j = 0; j < 8; ++j) qf[d][j] *= l2e;
    }

    f32x16 ot0 = zero16(), ot1 = zero16();
    float m = -1e30f, lp = 0.f;

    int krow = threadIdx.x >> 3, kc = threadIdx.x & 7;   // K stage: row, 16B chunk
    int ve   = threadIdx.x >> 2, vc = threadIdx.x & 3;   // V stage: e-row, 16B chunk

#define STAGE_KV(buf, kt)                                                                \
    {                                                                                    \
        gload16(Kb + ((size_t)(kt) * 32 + krow) * Ee + ((kc ^ (krow & 7)) * 8),          \
                &Klds[buf][wave * 512]);                                                 \
        gload16(Vb + (size_t)ve * Ss + (kt) * 32 + ((vc ^ (ve & 3)) * 8),                \
                &Vlds[buf][wave * 512]);                                                 \
    }

    STAGE_KV(0, 0);
    int cur = 0;
    int qk7 = ql & 7, q3 = ql & 3;
    for (int kt = 0; kt <= ktmax; ++kt) {
        __syncthreads();   // staged tile kt visible; prior reads of buf cur^1 done
        if (kt < ktmax) STAGE_KV(cur ^ 1, kt + 1);
        if (kt <= qt32) {
            // K fragments from LDS (swizzled chunks)
            f16x8 kf0 = *(const f16x8*)&Klds[cur][ql * 64 + (((0 + hi) ^ qk7) * 8)];
            f16x8 kf1 = *(const f16x8*)&Klds[cur][ql * 64 + (((2 + hi) ^ qk7) * 8)];
            f16x8 kf2 = *(const f16x8*)&Klds[cur][ql * 64 + (((4 + hi) ^ qk7) * 8)];
            f16x8 kf3 = *(const f16x8*)&Klds[cur][ql * 64 + (((6 + hi) ^ qk7) * 8)];

            f32x16 s = zero16();
            __builtin_amdgcn_s_setprio(1);
            s = __builtin_amdgcn_mfma_f32_32x32x16_f16(kf0, qf[0], s, 0, 0, 0);
            s = __builtin_amdgcn_mfma_f32_32x32x16_f16(kf1, qf[1], s, 0, 0, 0);
            s = __builtin_amdgcn_mfma_f32_32x32x16_f16(kf2, qf[2], s, 0, 0, 0);
            s = __builtin_amdgcn_mfma_f32_32x32x16_f16(kf3, qf[3], s, 0, 0, 0);
            __builtin_amdgcn_s_setprio(0);

            if (kt == qt32) {  // causal mask on the diagonal tile
#pragma unroll
                for (int r = 0; r < 16; ++r) {
                    int kloc = (r & 3) + 8 * (r >> 2) + 4 * hi;
                    if (kloc > ql) s[r] = -1e30f;
                }
            }

            float mt = s[0];
#pragma unroll
            for (int r = 1; r < 16; ++r) mt = fmaxf(mt, s[r]);
            mt = fmaxf(mt, __shfl_xor(mt, 32));
            if (!__all(mt <= m + 8.0f)) {      // T13 defer-max
                float mn = fmaxf(m, mt);
                float sc = exp2_fast(m - mn);
#pragma unroll
                for (int r = 0; r < 16; ++r) { ot0[r] *= sc; ot1[r] *= sc; }
                lp *= sc;
                m = mn;
            }
            float rs = 0.f;
#pragma unroll
            for (int r = 0; r < 16; ++r) { s[r] = exp2_fast(s[r] - m); rs += s[r]; }
            lp += rs;

            // pack P to f16; build PV B-frags with 4 xor-32 shuffles
            unsigned w[8];
#pragma unroll
            for (int mm = 0; mm < 8; ++mm)
                asm("v_cvt_pkrtz_f16_f32 %0, %1, %2" : "=v"(w[mm]) : "v"(s[2 * mm]), "v"(s[2 * mm + 1]));
            unsigned t0 = (unsigned)__shfl_xor((int)(hi ? w[0] : w[2]), 32);
            unsigned t1 = (unsigned)__shfl_xor((int)(hi ? w[1] : w[3]), 32);
            unsigned t2 = (unsigned)__shfl_xor((int)(hi ? w[4] : w[6]), 32);
            unsigned t3 = (unsigned)__shfl_xor((int)(hi ? w[5] : w[7]), 32);
            union { unsigned u[4]; f16x8 v; } pb0, pb1;
            pb0.u[0] = hi ? t0 : w[0];  pb0.u[1] = hi ? t1 : w[1];
            pb0.u[2] = hi ? w[2] : t0;  pb0.u[3] = hi ? w[3] : t1;
            pb1.u[0] = hi ? t2 : w[4];  pb1.u[1] = hi ? t3 : w[5];
            pb1.u[2] = hi ? w[6] : t2;  pb1.u[3] = hi ? w[7] : t3;

            // V^T fragments from LDS (swizzled chunks)
            f16x8 va00 = *(const f16x8*)&Vlds[cur][ql * 32 + ((hi ^ q3) * 8)];
            f16x8 va01 = *(const f16x8*)&Vlds[cur][ql * 32 + (((2 + hi) ^ q3) * 8)];
            f16x8 va10 = *(const f16x8*)&Vlds[cur][(32 + ql) * 32 + ((hi ^ q3) * 8)];
            f16x8 va11 = *(const f16x8*)&Vlds[cur][(32 + ql) * 32 + (((2 + hi) ^ q3) * 8)];

            __builtin_amdgcn_s_setprio(1);
            ot0 = __builtin_amdgcn_mfma_f32_32x32x16_f16(va00, pb0.v, ot0, 0, 0, 0);
            ot0 = __builtin_amdgcn_mfma_f32_32x32x16_f16(va01, pb1.v, ot0, 0, 0, 0);
            ot1 = __builtin_amdgcn_mfma_f32_32x32x16_f16(va10, pb0.v, ot1, 0, 0, 0);
            ot1 = __builtin_amdgcn_mfma_f32_32x32x16_f16(va11, pb1.v, ot1, 0, 0, 0);
            __builtin_amdgcn_s_setprio(0);
        }
        cur ^= 1;
    }
#undef STAGE_KV

    float lf = lp + __shfl_xor(lp, 32);
    float inv = 1.0f / lf;
    int b = bh >> 3, h = bh & 7;
    int qs = qg & 7;
    half_t* cb = ctx + ((size_t)b * Ss + qg) * Ff;
#pragma unroll
    for (int g = 0; g < 4; ++g) {
        h16x4 v0, v1;
#pragma unroll
        for (int j = 0; j < 4; ++j) {
            v0[j] = (half_t)(ot0[g * 4 + j] * inv);
            v1[j] = (half_t)(ot1[g * 4 + j] * inv);
        }
        *(h16x4*)(cb + (h * 8 + (g ^ qs)) * 8 + 4 * hi)       = v0;
        *(h16x4*)(cb + (h * 8 + ((g + 4) ^ qs)) * 8 + 4 * hi) = v1;
    }
}

// ---------------- output projection: same 2-phase GEMM, C[16384,512] f32 ----------------
__global__ __launch_bounds__(256, 2) void k_proj(const half_t* __restrict__ A,    // ctx (swizzled)
                                                 const half_t* __restrict__ Bw,   // WoT (swizzled)
                                                 float* __restrict__ out) {
    __shared__ __attribute__((aligned(16))) half_t Ab[2][128 * 64];
    __shared__ __attribute__((aligned(16))) half_t Bbuf[2][128 * 64];

    int bid = blockIdx.x;
    int virt = (bid & 7) * 64 + (bid >> 3);
    int bm = virt >> 2, bn = virt & 3;
    int m0 = bm * 128, n0 = bn * 128;

    int wave = threadIdx.x >> 6, lane = threadIdx.x & 63;
    int ar = lane & 15, kg = lane >> 4;
    int wm = wave >> 1, wn = wave & 1;
    int lr = lane >> 3, lc = lane & 7;

    f32x4 acc[4][4];
#pragma unroll
    for (int i = 0; i < 4; ++i)
#pragma unroll
        for (int j = 0; j < 4; ++j) acc[i][j] = (f32x4){0, 0, 0, 0};

#define STAGE_PRJ(buf, kt)                                                              \
    {                                                                                   \
        _Pragma("unroll")                                                               \
        for (int i = 0; i < 4; ++i) {                                                   \
            int seg = wave * 4 + i;                                                     \
            int row = seg * 8 + lr;                                                     \
            gload16(A  + (size_t)(m0 + row) * Ff + (kt) * 64 + lc * 8, &Ab[buf][seg * 512]);   \
            gload16(Bw + (size_t)(n0 + row) * Ff + (kt) * 64 + lc * 8, &Bbuf[buf][seg * 512]); \
        }                                                                               \
    }

    STAGE_PRJ(0, 0);
    __syncthreads();
    int cur = 0;
    for (int kt = 0; kt < 8; ++kt) {
        if (kt < 7) STAGE_PRJ(cur ^ 1, kt + 1);
        f16x8 bf[4][2];
#pragma unroll
        for (int n = 0; n < 4; ++n) {
            int row = wn * 64 + n * 16 + ar;
#pragma unroll
            for (int kh = 0; kh < 2; ++kh)
                bf[n][kh] = *(const f16x8*)&Bbuf[cur][row * 64 + (((kg + kh * 4)) ^ (row & 7)) * 8];
        }
#pragma unroll
        for (int mi = 0; mi < 4; ++mi) {
            int row = wm * 64 + mi * 16 + ar;
            f16x8 a0 = *(const f16x8*)&Ab[cur][row * 64 + ((kg)     ^ (row & 7)) * 8];
            f16x8 a1 = *(const f16x8*)&Ab[cur][row * 64 + ((kg + 4) ^ (row & 7)) * 8];
#pragma unroll
            for (int n = 0; n < 4; ++n) {
                acc[mi][n] = __builtin_amdgcn_mfma_f32_16x16x32_f16(a0, bf[n][0], acc[mi][n], 0, 0, 0);
                acc[mi][n] = __builtin_amdgcn_mfma_f32_16x16x32_f16(a1, bf[n][1], acc[mi][n], 0, 0, 0);
            }
        }
        __syncthreads();
        cur ^= 1;
    }
#pragma unroll
    for (int sn = 0; sn < 4; ++sn)
#pragma unroll
        for (int mi = 0; mi < 4; ++mi)
#pragma unroll
            for (int r = 0; r < 4; ++r) {
                int sg = m0 + wm * 64 + mi * 16 + kg * 4 + r;
                out[(size_t)sg * Oo + n0 + wn * 64 + sn * 16 + ar] = acc[mi][sn][r];
            }
#undef STAGE_PRJ
}

extern "C" void kernel_launch(void* const* d_in, const int* in_sizes, int n_in,
                              void* d_out, int out_size, void* d_ws, size_t ws_size,
                              hipStream_t stream) {
    const float* x  = (const float*)d_in[0];
    const float* Wq = (const float*)d_in[1];
    const float* Wk = (const float*)d_in[2];
    const float* Wv = (const float*)d_in[3];
    const float* Wo = (const float*)d_in[4];
    float* out = (float*)d_out;

    // workspace (all f16, fully rewritten every call): ~82 MB
    char* ws = (char*)d_ws;
    size_t off = 0;
    half_t* xh   = (half_t*)(ws + off); off += (size_t)Bb * Ss * Dd * 2;      // swizzled
    half_t* Wcat = (half_t*)(ws + off); off += (size_t)Ncat * Dd * 2;         // swizzled
    half_t* WoT  = (half_t*)(ws + off); off += (size_t)Oo * Ff * 2;           // swizzled
    half_t* Qd   = (half_t*)(ws + off); off += (size_t)Bb * Hh * Ss * Ee * 2; // plain [bh][s][e]
    half_t* Kd   = (half_t*)(ws + off); off += (size_t)Bb * Hh * Ss * Ee * 2; // plain [bh][s][e]
    half_t* Vtd  = (half_t*)(ws + off); off += (size_t)Bb * Hh * Ss * Ee * 2; // plain [bh][e][s]
    half_t* ctx  = (half_t*)(ws + off); off += (size_t)Bb * Ss * Ff * 2;      // swizzled

    k_cvt_x<<<4096, 256, 0, stream>>>(x, xh);
    k_cvt_w<<<512, 256, 0, stream>>>(Wq, Wk, Wv, Wo, Wcat, WoT);
    k_qkv<<<1536, 256, 0, stream>>>(xh, Wcat, Qd, Kd, Vtd);
    k_attn<<<1024, 256, 0, stream>>>(Qd, Kd, Vtd, ctx);
    k_proj<<<512, 256, 0, stream>>>(ctx, WoT, out);
}